// Round 1
// baseline (2041.971 us; speedup 1.0000x reference)
//
#include <hip/hip_runtime.h>

#define HID 128

// ---------------- scatter: layer 1 (dim 7) ----------------
__global__ void scatter_d7(const float* __restrict__ x, const float* __restrict__ ea,
                           const int* __restrict__ src, const int* __restrict__ dst,
                           const float* __restrict__ We, const float* __restrict__ be,
                           float* __restrict__ agg, int E)
{
    int e = blockIdx.x * blockDim.x + threadIdx.x;
    if (e >= E) return;
    float a0 = ea[e * 3 + 0], a1 = ea[e * 3 + 1], a2 = ea[e * 3 + 2];
    int s = src[e], d = dst[e];
#pragma unroll
    for (int c = 0; c < 7; ++c) {
        float v = be[c] + a0 * We[c] + a1 * We[7 + c] + a2 * We[14 + c] + x[s * 7 + c];
        v = fmaxf(v, 0.f);
        atomicAdd(&agg[d * 7 + c], v);
    }
}

// ---------------- scatter: layers 2/3 (dim 128) ----------------
__global__ void scatter_d128(const float* __restrict__ h, const float* __restrict__ ea,
                             const int* __restrict__ src, const int* __restrict__ dst,
                             const float* __restrict__ We, const float* __restrict__ be,
                             float* __restrict__ agg, int E)
{
    long long idx = (long long)blockIdx.x * blockDim.x + threadIdx.x;
    long long total = (long long)E * HID;
    if (idx >= total) return;
    int e = (int)(idx >> 7);
    int c = (int)(idx & 127);
    float a0 = ea[e * 3 + 0], a1 = ea[e * 3 + 1], a2 = ea[e * 3 + 2];
    int s = src[e], d = dst[e];
    float v = be[c];
    v = fmaf(a0, We[c], v);
    v = fmaf(a1, We[HID + c], v);
    v = fmaf(a2, We[2 * HID + c], v);
    v += h[(long long)s * HID + c];
    v = fmaxf(v, 0.f);
    atomicAdd(&agg[(long long)d * HID + c], v);
}

// ---------------- MLP GEMM: C[N,128] = op((A (+A2)) @ W[K,128] + b) ----------------
template <int K, bool HASADD, bool RELU>
__global__ void mlp_gemm(const float* __restrict__ A, const float* __restrict__ A2,
                         const float* __restrict__ W, const float* __restrict__ bias,
                         float* __restrict__ C, int N)
{
    long long gid = (long long)blockIdx.x * blockDim.x + threadIdx.x;
    long long total = (long long)N * 32;
    if (gid >= total) return;
    int n = (int)(gid >> 5);
    int c4 = (int)(gid & 31);
    const float4* W4 = (const float4*)W;
    const float4* B4 = (const float4*)bias;
    float4 acc = B4[c4];
    const float* arow = A + (long long)n * K;
    const float* arow2 = A2 ? (A2 + (long long)n * K) : nullptr;
#pragma unroll 4
    for (int k = 0; k < K; ++k) {
        float a = arow[k];
        if (HASADD) a += arow2[k];
        float4 w = W4[k * 32 + c4];
        acc.x = fmaf(a, w.x, acc.x);
        acc.y = fmaf(a, w.y, acc.y);
        acc.z = fmaf(a, w.z, acc.z);
        acc.w = fmaf(a, w.w, acc.w);
    }
    if (RELU) {
        acc.x = fmaxf(acc.x, 0.f); acc.y = fmaxf(acc.y, 0.f);
        acc.z = fmaxf(acc.z, 0.f); acc.w = fmaxf(acc.w, 0.f);
    }
    ((float4*)C)[gid] = acc;
}

// ---------------- BN stats: per-channel sum / sumsq ----------------
__global__ void bn_stats(const float* __restrict__ h, float* __restrict__ sums, int N)
{
    __shared__ float ls[256], lq[256];
    int t = threadIdx.x;
    int c = t & 127, half = t >> 7;
    int nend = (blockIdx.x + 1) * 512;
    if (nend > N) nend = N;
    float s = 0.f, q = 0.f;
    for (int n = blockIdx.x * 512 + half; n < nend; n += 2) {
        float v = h[(long long)n * HID + c];
        s += v;
        q = fmaf(v, v, q);
    }
    ls[t] = s; lq[t] = q;
    __syncthreads();
    if (t < 128) {
        atomicAdd(&sums[c], ls[t] + ls[t + 128]);
        atomicAdd(&sums[128 + c], lq[t] + lq[t + 128]);
    }
}

__global__ void bn_finalize(const float* __restrict__ sums, const float* __restrict__ g,
                            const float* __restrict__ bt, float* __restrict__ ab, int N)
{
    int c = threadIdx.x;
    if (c < 128) {
        float inv = 1.f / (float)N;
        float mu = sums[c] * inv;
        float var = sums[128 + c] * inv - mu * mu;
        float rs = rsqrtf(fmaxf(var, 0.f) + 1e-5f);
        float a = g[c] * rs;
        ab[c] = a;
        ab[128 + c] = bt[c] - a * mu;
    }
}

__global__ void bn_apply_relu(const float* __restrict__ h, const float* __restrict__ ab,
                              float* __restrict__ out, long long total)
{
    long long i = (long long)blockIdx.x * blockDim.x + threadIdx.x;
    if (i >= total) return;
    int c = (int)(i & 127);
    float v = fmaf(h[i], ab[c], ab[128 + c]);
    out[i] = fmaxf(v, 0.f);
}

// ---------------- global mean pool (scatter) ----------------
__global__ void pool_scatter(const float* __restrict__ h, const int* __restrict__ batch,
                             float* __restrict__ pools, float* __restrict__ cnt, int N)
{
    long long i = (long long)blockIdx.x * blockDim.x + threadIdx.x;
    long long total = (long long)N * HID;
    if (i >= total) return;
    int n = (int)(i >> 7);
    int c = (int)(i & 127);
    int g = batch[n];
    atomicAdd(&pools[(long long)g * HID + c], h[i]);
    if (c == 0) atomicAdd(&cnt[g], 1.f);
}

// ---------------- head: relu(p@Wf1+bf1)@Wf2+bf2 ----------------
__global__ void head_kernel(const float* __restrict__ pools, const float* __restrict__ cnt,
                            const float* __restrict__ Wf1, const float* __restrict__ bf1,
                            const float* __restrict__ Wf2, const float* __restrict__ bf2,
                            float* __restrict__ out, int G)
{
    int g = blockIdx.x;
    int t = threadIdx.x; // 64 threads = 1 wave
    __shared__ float p[128];
    float inv = 1.f / fmaxf(cnt[g], 1.f);
    p[t] = pools[g * 128 + t] * inv;
    p[t + 64] = pools[g * 128 + t + 64] * inv;
    __syncthreads();
    float o = bf1[t];
#pragma unroll 8
    for (int k = 0; k < 128; ++k) o = fmaf(p[k], Wf1[k * 64 + t], o);
    o = fmaxf(o, 0.f);
    float prod = o * Wf2[t];
#pragma unroll
    for (int off = 32; off > 0; off >>= 1) prod += __shfl_down(prod, off);
    if (t == 0) out[g] = prod + bf2[0];
}

extern "C" void kernel_launch(void* const* d_in, const int* in_sizes, int n_in,
                              void* d_out, int out_size, void* d_ws, size_t ws_size,
                              hipStream_t stream)
{
    const float* x     = (const float*)d_in[0];
    const float* ea    = (const float*)d_in[1];
    const int*   eidx  = (const int*)d_in[2];
    const int*   batch = (const int*)d_in[3];
    const float* We1 = (const float*)d_in[4];  const float* be1 = (const float*)d_in[5];
    const float* W11 = (const float*)d_in[6];  const float* b11 = (const float*)d_in[7];
    const float* W12 = (const float*)d_in[8];  const float* b12 = (const float*)d_in[9];
    const float* g1  = (const float*)d_in[10]; const float* bt1 = (const float*)d_in[11];
    const float* We2 = (const float*)d_in[12]; const float* be2 = (const float*)d_in[13];
    const float* W21 = (const float*)d_in[14]; const float* b21 = (const float*)d_in[15];
    const float* W22 = (const float*)d_in[16]; const float* b22 = (const float*)d_in[17];
    const float* g2  = (const float*)d_in[18]; const float* bt2 = (const float*)d_in[19];
    const float* We3 = (const float*)d_in[20]; const float* be3 = (const float*)d_in[21];
    const float* W31 = (const float*)d_in[22]; const float* b31 = (const float*)d_in[23];
    const float* W32 = (const float*)d_in[24]; const float* b32 = (const float*)d_in[25];
    const float* g3  = (const float*)d_in[26]; const float* bt3 = (const float*)d_in[27];
    const float* Wf1 = (const float*)d_in[28]; const float* bf1 = (const float*)d_in[29];
    const float* Wf2 = (const float*)d_in[30]; const float* bf2 = (const float*)d_in[31];

    const int N = in_sizes[0] / 7;
    const int E = in_sizes[1] / 3;
    const int G = out_size;
    const int* src = eidx;
    const int* dst = eidx + E;

    float* ws = (float*)d_ws;
    float* buf_h   = ws;                          // N*128
    float* buf_agg = buf_h + (size_t)N * HID;     // N*128
    float* buf_t   = buf_agg + (size_t)N * HID;   // N*128
    float* bnsums  = buf_t + (size_t)N * HID;     // 256
    float* bnab    = bnsums + 256;                // 256
    float* pools   = bnab + 256;                  // G*128
    float* cntp    = pools + (size_t)G * HID;     // G

    const long long NH = (long long)N * HID;
    const int blk = 256;
    const unsigned grid_nh   = (unsigned)((NH + blk - 1) / blk);
    const unsigned grid_gemm = (unsigned)(((long long)N * 32 + blk - 1) / blk);
    const unsigned grid_edge = (unsigned)(((long long)E * HID + blk - 1) / blk);
    const unsigned grid_bn   = (unsigned)((N + 511) / 512);

    // ---------- layer 1 ----------
    hipMemsetAsync(buf_agg, 0, (size_t)N * 7 * sizeof(float), stream);
    scatter_d7<<<(E + blk - 1) / blk, blk, 0, stream>>>(x, ea, src, dst, We1, be1, buf_agg, E);
    mlp_gemm<7, true, true><<<grid_gemm, blk, 0, stream>>>(x, buf_agg, W11, b11, buf_t, N);
    mlp_gemm<128, false, false><<<grid_gemm, blk, 0, stream>>>(buf_t, nullptr, W12, b12, buf_agg, N);
    hipMemsetAsync(bnsums, 0, 256 * sizeof(float), stream);
    bn_stats<<<grid_bn, blk, 0, stream>>>(buf_agg, bnsums, N);
    bn_finalize<<<1, 128, 0, stream>>>(bnsums, g1, bt1, bnab, N);
    bn_apply_relu<<<grid_nh, blk, 0, stream>>>(buf_agg, bnab, buf_h, NH);

    // ---------- layer 2 ----------
    hipMemsetAsync(buf_agg, 0, (size_t)NH * sizeof(float), stream);
    scatter_d128<<<grid_edge, blk, 0, stream>>>(buf_h, ea, src, dst, We2, be2, buf_agg, E);
    mlp_gemm<128, true, true><<<grid_gemm, blk, 0, stream>>>(buf_h, buf_agg, W21, b21, buf_t, N);
    mlp_gemm<128, false, false><<<grid_gemm, blk, 0, stream>>>(buf_t, nullptr, W22, b22, buf_agg, N);
    hipMemsetAsync(bnsums, 0, 256 * sizeof(float), stream);
    bn_stats<<<grid_bn, blk, 0, stream>>>(buf_agg, bnsums, N);
    bn_finalize<<<1, 128, 0, stream>>>(bnsums, g2, bt2, bnab, N);
    bn_apply_relu<<<grid_nh, blk, 0, stream>>>(buf_agg, bnab, buf_h, NH);

    // ---------- layer 3 ----------
    hipMemsetAsync(buf_agg, 0, (size_t)NH * sizeof(float), stream);
    scatter_d128<<<grid_edge, blk, 0, stream>>>(buf_h, ea, src, dst, We3, be3, buf_agg, E);
    mlp_gemm<128, true, true><<<grid_gemm, blk, 0, stream>>>(buf_h, buf_agg, W31, b31, buf_t, N);
    mlp_gemm<128, false, false><<<grid_gemm, blk, 0, stream>>>(buf_t, nullptr, W32, b32, buf_agg, N);
    hipMemsetAsync(bnsums, 0, 256 * sizeof(float), stream);
    bn_stats<<<grid_bn, blk, 0, stream>>>(buf_agg, bnsums, N);
    bn_finalize<<<1, 128, 0, stream>>>(bnsums, g3, bt3, bnab, N);
    bn_apply_relu<<<grid_nh, blk, 0, stream>>>(buf_agg, bnab, buf_h, NH);

    // ---------- pool + head ----------
    hipMemsetAsync(pools, 0, ((size_t)G * HID + G) * sizeof(float), stream);
    pool_scatter<<<grid_nh, blk, 0, stream>>>(buf_h, batch, pools, cntp, N);
    head_kernel<<<G, 64, 0, stream>>>(pools, cntp, Wf1, bf1, Wf2, bf2, (float*)d_out, G);
}

// Round 2
// 1654.467 us; speedup vs baseline: 1.2342x; 1.2342x over previous
//
#include <hip/hip_runtime.h>

#define HID 128

// ================= CSR build =================
__global__ void hist_kernel(const int* __restrict__ dst, int* __restrict__ cnt, int E)
{
    int e = blockIdx.x * blockDim.x + threadIdx.x;
    if (e < E) atomicAdd(&cnt[dst[e]], 1);
}

// per-block exclusive scan of 256 ints, emits block totals
__global__ void scan_block(const int* __restrict__ cnt, int* __restrict__ excl,
                           int* __restrict__ partials, int Nn)
{
    __shared__ int ls[256];
    int i = blockIdx.x * 256 + threadIdx.x;
    int v = (i < Nn) ? cnt[i] : 0;
    ls[threadIdx.x] = v;
    __syncthreads();
    for (int off = 1; off < 256; off <<= 1) {
        int t = (threadIdx.x >= off) ? ls[threadIdx.x - off] : 0;
        __syncthreads();
        ls[threadIdx.x] += t;
        __syncthreads();
    }
    if (i < Nn) excl[i] = ls[threadIdx.x] - v;
    if (threadIdx.x == 255) partials[blockIdx.x] = ls[255];
}

// single block: exclusive scan of block totals (nb <= 256); also writes offsets[Nn]=E
__global__ void scan_partials(int* __restrict__ partials, int nb, int* __restrict__ offsets,
                              int Nn, int E)
{
    __shared__ int ls[256];
    int t = threadIdx.x;
    int v = (t < nb) ? partials[t] : 0;
    ls[t] = v;
    __syncthreads();
    for (int off = 1; off < 256; off <<= 1) {
        int x = (t >= off) ? ls[t - off] : 0;
        __syncthreads();
        ls[t] += x;
        __syncthreads();
    }
    if (t < nb) partials[t] = ls[t] - v;
    if (t == 0) offsets[Nn] = E;
}

// add block prefix; write offsets and cursor copy
__global__ void scan_add(const int* __restrict__ excl, const int* __restrict__ partials,
                         int* __restrict__ offsets, int* __restrict__ cursor, int Nn)
{
    int i = blockIdx.x * 256 + threadIdx.x;
    if (i < Nn) {
        int o = excl[i] + partials[blockIdx.x];
        offsets[i] = o;
        cursor[i] = o;
    }
}

__global__ void fill_kernel(const int* __restrict__ dst, int* __restrict__ cursor,
                            int* __restrict__ elist, int E)
{
    int e = blockIdx.x * blockDim.x + threadIdx.x;
    if (e < E) {
        int pos = atomicAdd(&cursor[dst[e]], 1);
        elist[pos] = e;
    }
}

// ================= layer 1 scatter (dim 7, atomic) =================
__global__ void scatter_d7(const float* __restrict__ x, const float* __restrict__ ea,
                           const int* __restrict__ src, const int* __restrict__ dst,
                           const float* __restrict__ We, const float* __restrict__ be,
                           float* __restrict__ agg, int E)
{
    int e = blockIdx.x * blockDim.x + threadIdx.x;
    if (e >= E) return;
    float a0 = ea[e * 3 + 0], a1 = ea[e * 3 + 1], a2 = ea[e * 3 + 2];
    int s = src[e], d = dst[e];
#pragma unroll
    for (int c = 0; c < 7; ++c) {
        float v = be[c] + a0 * We[c] + a1 * We[7 + c] + a2 * We[14 + c] + x[s * 7 + c];
        v = fmaxf(v, 0.f);
        atomicAdd(&agg[d * 7 + c], v);
    }
}

// ================= layers 2/3: CSR gather-aggregate (dim 128) =================
// one wave (64 lanes) per dst node; lane handles channels 2*lane, 2*lane+1
__global__ void gather_d128(const float* __restrict__ h, const float* __restrict__ ea,
                            const int* __restrict__ srcArr,
                            const int* __restrict__ offsets, const int* __restrict__ elist,
                            const float* __restrict__ We, const float* __restrict__ be,
                            float* __restrict__ agg, int Nn)
{
    int node = blockIdx.x * (blockDim.x >> 6) + (threadIdx.x >> 6);
    if (node >= Nn) return;
    int lane = threadIdx.x & 63;
    int beg = offsets[node], end = offsets[node + 1];
    const float2* W2 = (const float2*)We;
    float2 w0 = W2[lane];
    float2 w1 = W2[64 + lane];
    float2 w2 = W2[128 + lane];
    float2 bb = ((const float2*)be)[lane];
    float accx = 0.f, accy = 0.f;

    int e = 0, s = 0;
    float a0 = 0.f, a1 = 0.f, a2 = 0.f;
    if (beg < end) {
        e = elist[beg]; s = srcArr[e];
        a0 = ea[e * 3]; a1 = ea[e * 3 + 1]; a2 = ea[e * 3 + 2];
    }
    for (int i = beg; i < end; ++i) {
        float2 hv = ((const float2*)(h + (size_t)s * HID))[lane];
        float ca0 = a0, ca1 = a1, ca2 = a2;
        if (i + 1 < end) {
            int e2 = elist[i + 1];
            s = srcArr[e2];
            a0 = ea[e2 * 3]; a1 = ea[e2 * 3 + 1]; a2 = ea[e2 * 3 + 2];
        }
        float vx = bb.x + hv.x;
        vx = fmaf(ca0, w0.x, vx); vx = fmaf(ca1, w1.x, vx); vx = fmaf(ca2, w2.x, vx);
        float vy = bb.y + hv.y;
        vy = fmaf(ca0, w0.y, vy); vy = fmaf(ca1, w1.y, vy); vy = fmaf(ca2, w2.y, vy);
        accx += fmaxf(vx, 0.f);
        accy += fmaxf(vy, 0.f);
    }
    float2 outv = {accx, accy};
    ((float2*)(agg + (size_t)node * HID))[lane] = outv;
}

// ================= MLP GEMM =================
template <int K, bool HASADD, bool RELU>
__global__ void mlp_gemm(const float* __restrict__ A, const float* __restrict__ A2,
                         const float* __restrict__ W, const float* __restrict__ bias,
                         float* __restrict__ C, int N)
{
    long long gid = (long long)blockIdx.x * blockDim.x + threadIdx.x;
    long long total = (long long)N * 32;
    if (gid >= total) return;
    int n = (int)(gid >> 5);
    int c4 = (int)(gid & 31);
    const float4* W4 = (const float4*)W;
    const float4* B4 = (const float4*)bias;
    float4 acc = B4[c4];
    const float* arow = A + (long long)n * K;
    const float* arow2 = A2 ? (A2 + (long long)n * K) : nullptr;
#pragma unroll 4
    for (int k = 0; k < K; ++k) {
        float a = arow[k];
        if (HASADD) a += arow2[k];
        float4 w = W4[k * 32 + c4];
        acc.x = fmaf(a, w.x, acc.x);
        acc.y = fmaf(a, w.y, acc.y);
        acc.z = fmaf(a, w.z, acc.z);
        acc.w = fmaf(a, w.w, acc.w);
    }
    if (RELU) {
        acc.x = fmaxf(acc.x, 0.f); acc.y = fmaxf(acc.y, 0.f);
        acc.z = fmaxf(acc.z, 0.f); acc.w = fmaxf(acc.w, 0.f);
    }
    ((float4*)C)[gid] = acc;
}

// ================= BN =================
__global__ void bn_stats(const float* __restrict__ h, float* __restrict__ sums, int N)
{
    __shared__ float ls[256], lq[256];
    int t = threadIdx.x;
    int c = t & 127, half = t >> 7;
    int nend = (blockIdx.x + 1) * 512;
    if (nend > N) nend = N;
    float s = 0.f, q = 0.f;
    for (int n = blockIdx.x * 512 + half; n < nend; n += 2) {
        float v = h[(long long)n * HID + c];
        s += v;
        q = fmaf(v, v, q);
    }
    ls[t] = s; lq[t] = q;
    __syncthreads();
    if (t < 128) {
        atomicAdd(&sums[c], ls[t] + ls[t + 128]);
        atomicAdd(&sums[128 + c], lq[t] + lq[t + 128]);
    }
}

__global__ void bn_finalize(const float* __restrict__ sums, const float* __restrict__ g,
                            const float* __restrict__ bt, float* __restrict__ ab, int N)
{
    int c = threadIdx.x;
    if (c < 128) {
        float inv = 1.f / (float)N;
        float mu = sums[c] * inv;
        float var = sums[128 + c] * inv - mu * mu;
        float rs = rsqrtf(fmaxf(var, 0.f) + 1e-5f);
        float a = g[c] * rs;
        ab[c] = a;
        ab[128 + c] = bt[c] - a * mu;
    }
}

__global__ void bn_apply_relu(const float* __restrict__ h, const float* __restrict__ ab,
                              float* __restrict__ out, long long total)
{
    long long i = (long long)blockIdx.x * blockDim.x + threadIdx.x;
    if (i >= total) return;
    int c = (int)(i & 127);
    float v = fmaf(h[i], ab[c], ab[128 + c]);
    out[i] = fmaxf(v, 0.f);
}

// ================= pool + head =================
__global__ void pool_scatter(const float* __restrict__ h, const int* __restrict__ batch,
                             float* __restrict__ pools, float* __restrict__ cnt, int N)
{
    long long i = (long long)blockIdx.x * blockDim.x + threadIdx.x;
    long long total = (long long)N * HID;
    if (i >= total) return;
    int n = (int)(i >> 7);
    int c = (int)(i & 127);
    int g = batch[n];
    atomicAdd(&pools[(long long)g * HID + c], h[i]);
    if (c == 0) atomicAdd(&cnt[g], 1.f);
}

__global__ void head_kernel(const float* __restrict__ pools, const float* __restrict__ cnt,
                            const float* __restrict__ Wf1, const float* __restrict__ bf1,
                            const float* __restrict__ Wf2, const float* __restrict__ bf2,
                            float* __restrict__ out, int G)
{
    int g = blockIdx.x;
    int t = threadIdx.x; // 64 threads = 1 wave
    __shared__ float p[128];
    float inv = 1.f / fmaxf(cnt[g], 1.f);
    p[t] = pools[g * 128 + t] * inv;
    p[t + 64] = pools[g * 128 + t + 64] * inv;
    __syncthreads();
    float o = bf1[t];
#pragma unroll 8
    for (int k = 0; k < 128; ++k) o = fmaf(p[k], Wf1[k * 64 + t], o);
    o = fmaxf(o, 0.f);
    float prod = o * Wf2[t];
#pragma unroll
    for (int off = 32; off > 0; off >>= 1) prod += __shfl_down(prod, off);
    if (t == 0) out[g] = prod + bf2[0];
}

extern "C" void kernel_launch(void* const* d_in, const int* in_sizes, int n_in,
                              void* d_out, int out_size, void* d_ws, size_t ws_size,
                              hipStream_t stream)
{
    const float* x     = (const float*)d_in[0];
    const float* ea    = (const float*)d_in[1];
    const int*   eidx  = (const int*)d_in[2];
    const int*   batch = (const int*)d_in[3];
    const float* We1 = (const float*)d_in[4];  const float* be1 = (const float*)d_in[5];
    const float* W11 = (const float*)d_in[6];  const float* b11 = (const float*)d_in[7];
    const float* W12 = (const float*)d_in[8];  const float* b12 = (const float*)d_in[9];
    const float* g1  = (const float*)d_in[10]; const float* bt1 = (const float*)d_in[11];
    const float* We2 = (const float*)d_in[12]; const float* be2 = (const float*)d_in[13];
    const float* W21 = (const float*)d_in[14]; const float* b21 = (const float*)d_in[15];
    const float* W22 = (const float*)d_in[16]; const float* b22 = (const float*)d_in[17];
    const float* g2  = (const float*)d_in[18]; const float* bt2 = (const float*)d_in[19];
    const float* We3 = (const float*)d_in[20]; const float* be3 = (const float*)d_in[21];
    const float* W31 = (const float*)d_in[22]; const float* b31 = (const float*)d_in[23];
    const float* W32 = (const float*)d_in[24]; const float* b32 = (const float*)d_in[25];
    const float* g3  = (const float*)d_in[26]; const float* bt3 = (const float*)d_in[27];
    const float* Wf1 = (const float*)d_in[28]; const float* bf1 = (const float*)d_in[29];
    const float* Wf2 = (const float*)d_in[30]; const float* bf2 = (const float*)d_in[31];

    const int N = in_sizes[0] / 7;
    const int E = in_sizes[1] / 3;
    const int G = out_size;
    const int* src = eidx;
    const int* dst = eidx + E;

    float* ws = (float*)d_ws;
    float* buf_h   = ws;                          // N*128
    float* buf_agg = buf_h + (size_t)N * HID;     // N*128
    float* buf_t   = buf_agg + (size_t)N * HID;   // N*128
    float* bnsums  = buf_t + (size_t)N * HID;     // 256
    float* bnab    = bnsums + 256;                // 256
    float* pools   = bnab + 256;                  // G*128
    float* cntp    = pools + (size_t)G * HID;     // G
    int*   icnt    = (int*)(cntp + G);            // N   (reused: histogram counts)
    int*   ioffs   = icnt + N;                    // N+1 (CSR offsets)
    int*   icur    = ioffs + N + 1;               // N   (fill cursors)
    int*   ielist  = icur + N;                    // E   (dst-grouped edge ids)
    int*   ipart   = ielist + E;                  // 256 (scan partials)
    int*   iexcl   = ipart + 256;                 // N   (scan temps)

    const long long NH = (long long)N * HID;
    const int blk = 256;
    const unsigned grid_nh   = (unsigned)((NH + blk - 1) / blk);
    const unsigned grid_gemm = (unsigned)(((long long)N * 32 + blk - 1) / blk);
    const unsigned grid_bn   = (unsigned)((N + 511) / 512);
    const unsigned grid_E    = (unsigned)((E + blk - 1) / blk);
    const unsigned nb_scan   = (unsigned)((N + 255) / 256);
    const unsigned grid_gather = (unsigned)((N + 3) / 4);   // 4 waves/block, 1 node/wave

    // ---------- build CSR (dst-grouped edge lists), once ----------
    hipMemsetAsync(icnt, 0, (size_t)N * sizeof(int), stream);
    hist_kernel<<<grid_E, blk, 0, stream>>>(dst, icnt, E);
    scan_block<<<nb_scan, 256, 0, stream>>>(icnt, iexcl, ipart, N);
    scan_partials<<<1, 256, 0, stream>>>(ipart, nb_scan, ioffs, N, E);
    scan_add<<<nb_scan, 256, 0, stream>>>(iexcl, ipart, ioffs, icur, N);
    fill_kernel<<<grid_E, blk, 0, stream>>>(dst, icur, ielist, E);

    // ---------- layer 1 ----------
    hipMemsetAsync(buf_agg, 0, (size_t)N * 7 * sizeof(float), stream);
    scatter_d7<<<grid_E, blk, 0, stream>>>(x, ea, src, dst, We1, be1, buf_agg, E);
    mlp_gemm<7, true, true><<<grid_gemm, blk, 0, stream>>>(x, buf_agg, W11, b11, buf_t, N);
    mlp_gemm<128, false, false><<<grid_gemm, blk, 0, stream>>>(buf_t, nullptr, W12, b12, buf_agg, N);
    hipMemsetAsync(bnsums, 0, 256 * sizeof(float), stream);
    bn_stats<<<grid_bn, blk, 0, stream>>>(buf_agg, bnsums, N);
    bn_finalize<<<1, 128, 0, stream>>>(bnsums, g1, bt1, bnab, N);
    bn_apply_relu<<<grid_nh, blk, 0, stream>>>(buf_agg, bnab, buf_h, NH);

    // ---------- layer 2 ----------
    gather_d128<<<grid_gather, 256, 0, stream>>>(buf_h, ea, src, ioffs, ielist, We2, be2, buf_agg, N);
    mlp_gemm<128, true, true><<<grid_gemm, blk, 0, stream>>>(buf_h, buf_agg, W21, b21, buf_t, N);
    mlp_gemm<128, false, false><<<grid_gemm, blk, 0, stream>>>(buf_t, nullptr, W22, b22, buf_agg, N);
    hipMemsetAsync(bnsums, 0, 256 * sizeof(float), stream);
    bn_stats<<<grid_bn, blk, 0, stream>>>(buf_agg, bnsums, N);
    bn_finalize<<<1, 128, 0, stream>>>(bnsums, g2, bt2, bnab, N);
    bn_apply_relu<<<grid_nh, blk, 0, stream>>>(buf_agg, bnab, buf_h, NH);

    // ---------- layer 3 ----------
    gather_d128<<<grid_gather, 256, 0, stream>>>(buf_h, ea, src, ioffs, ielist, We3, be3, buf_agg, N);
    mlp_gemm<128, true, true><<<grid_gemm, blk, 0, stream>>>(buf_h, buf_agg, W31, b31, buf_t, N);
    mlp_gemm<128, false, false><<<grid_gemm, blk, 0, stream>>>(buf_t, nullptr, W32, b32, buf_agg, N);
    hipMemsetAsync(bnsums, 0, 256 * sizeof(float), stream);
    bn_stats<<<grid_bn, blk, 0, stream>>>(buf_agg, bnsums, N);
    bn_finalize<<<1, 128, 0, stream>>>(bnsums, g3, bt3, bnab, N);
    bn_apply_relu<<<grid_nh, blk, 0, stream>>>(buf_agg, bnab, buf_h, NH);

    // ---------- pool + head ----------
    hipMemsetAsync(pools, 0, ((size_t)G * HID + G) * sizeof(float), stream);
    pool_scatter<<<grid_nh, blk, 0, stream>>>(buf_h, batch, pools, cntp, N);
    head_kernel<<<G, 64, 0, stream>>>(pools, cntp, Wf1, bf1, Wf2, bf2, (float*)d_out, G);
}

// Round 3
// 1399.187 us; speedup vs baseline: 1.4594x; 1.1824x over previous
//
#include <hip/hip_runtime.h>

#define HID 128

// ================= CSR build =================
__global__ void hist_kernel(const int* __restrict__ dst, int* __restrict__ cnt, int E)
{
    int e = blockIdx.x * blockDim.x + threadIdx.x;
    if (e < E) atomicAdd(&cnt[dst[e]], 1);
}

__global__ void scan_block(const int* __restrict__ cnt, int* __restrict__ excl,
                           int* __restrict__ partials, int Nn)
{
    __shared__ int ls[256];
    int i = blockIdx.x * 256 + threadIdx.x;
    int v = (i < Nn) ? cnt[i] : 0;
    ls[threadIdx.x] = v;
    __syncthreads();
    for (int off = 1; off < 256; off <<= 1) {
        int t = (threadIdx.x >= off) ? ls[threadIdx.x - off] : 0;
        __syncthreads();
        ls[threadIdx.x] += t;
        __syncthreads();
    }
    if (i < Nn) excl[i] = ls[threadIdx.x] - v;
    if (threadIdx.x == 255) partials[blockIdx.x] = ls[255];
}

__global__ void scan_partials(int* __restrict__ partials, int nb, int* __restrict__ offsets,
                              int Nn, int E)
{
    __shared__ int ls[256];
    int t = threadIdx.x;
    int v = (t < nb) ? partials[t] : 0;
    ls[t] = v;
    __syncthreads();
    for (int off = 1; off < 256; off <<= 1) {
        int x = (t >= off) ? ls[t - off] : 0;
        __syncthreads();
        ls[t] += x;
        __syncthreads();
    }
    if (t < nb) partials[t] = ls[t] - v;
    if (t == 0) offsets[Nn] = E;
}

__global__ void scan_add(const int* __restrict__ excl, const int* __restrict__ partials,
                         int* __restrict__ offsets, int* __restrict__ cursor, int Nn)
{
    int i = blockIdx.x * 256 + threadIdx.x;
    if (i < Nn) {
        int o = excl[i] + partials[blockIdx.x];
        offsets[i] = o;
        cursor[i] = o;
    }
}

__global__ void fill_kernel(const int* __restrict__ dst, int* __restrict__ cursor,
                            int* __restrict__ elist, int E)
{
    int e = blockIdx.x * blockDim.x + threadIdx.x;
    if (e < E) {
        int pos = atomicAdd(&cursor[dst[e]], 1);
        elist[pos] = e;
    }
}

// ================= layer 1: CSR gather (dim 7) =================
// 8 threads per node: lane c in [0,8), channels 0..6 active
__global__ void gather_d7(const float* __restrict__ x, const float* __restrict__ ea,
                          const int* __restrict__ srcArr,
                          const int* __restrict__ offsets, const int* __restrict__ elist,
                          const float* __restrict__ We, const float* __restrict__ be,
                          float* __restrict__ agg, int Nn)
{
    int tid = blockIdx.x * blockDim.x + threadIdx.x;
    int node = tid >> 3;
    int c = tid & 7;
    if (node >= Nn) return;
    float w0 = 0.f, w1 = 0.f, w2 = 0.f, b = 0.f;
    if (c < 7) { w0 = We[c]; w1 = We[7 + c]; w2 = We[14 + c]; b = be[c]; }
    int beg = offsets[node], end = offsets[node + 1];
    float acc = 0.f;
    for (int i = beg; i < end; ++i) {
        int e = elist[i];
        int s = srcArr[e];
        float a0 = ea[e * 3], a1 = ea[e * 3 + 1], a2 = ea[e * 3 + 2];
        float v = b;
        v = fmaf(a0, w0, v);
        v = fmaf(a1, w1, v);
        v = fmaf(a2, w2, v);
        if (c < 7) v += x[s * 7 + c];
        acc += fmaxf(v, 0.f);
    }
    if (c < 7) agg[node * 7 + c] = acc;
}

// ================= layers 2/3: CSR gather-aggregate (dim 128) =================
__global__ void gather_d128(const float* __restrict__ h, const float* __restrict__ ea,
                            const int* __restrict__ srcArr,
                            const int* __restrict__ offsets, const int* __restrict__ elist,
                            const float* __restrict__ We, const float* __restrict__ be,
                            float* __restrict__ agg, int Nn)
{
    int node = blockIdx.x * (blockDim.x >> 6) + (threadIdx.x >> 6);
    if (node >= Nn) return;
    int lane = threadIdx.x & 63;
    int beg = offsets[node], end = offsets[node + 1];
    const float2* W2 = (const float2*)We;
    float2 w0 = W2[lane];
    float2 w1 = W2[64 + lane];
    float2 w2 = W2[128 + lane];
    float2 bb = ((const float2*)be)[lane];
    float accx = 0.f, accy = 0.f;

    int e = 0, s = 0;
    float a0 = 0.f, a1 = 0.f, a2 = 0.f;
    if (beg < end) {
        e = elist[beg]; s = srcArr[e];
        a0 = ea[e * 3]; a1 = ea[e * 3 + 1]; a2 = ea[e * 3 + 2];
    }
    for (int i = beg; i < end; ++i) {
        float2 hv = ((const float2*)(h + (size_t)s * HID))[lane];
        float ca0 = a0, ca1 = a1, ca2 = a2;
        if (i + 1 < end) {
            int e2 = elist[i + 1];
            s = srcArr[e2];
            a0 = ea[e2 * 3]; a1 = ea[e2 * 3 + 1]; a2 = ea[e2 * 3 + 2];
        }
        float vx = bb.x + hv.x;
        vx = fmaf(ca0, w0.x, vx); vx = fmaf(ca1, w1.x, vx); vx = fmaf(ca2, w2.x, vx);
        float vy = bb.y + hv.y;
        vy = fmaf(ca0, w0.y, vy); vy = fmaf(ca1, w1.y, vy); vy = fmaf(ca2, w2.y, vy);
        accx += fmaxf(vx, 0.f);
        accy += fmaxf(vy, 0.f);
    }
    float2 outv = {accx, accy};
    ((float2*)(agg + (size_t)node * HID))[lane] = outv;
}

// ================= MLP GEMM =================
template <int K, bool HASADD, bool RELU>
__global__ void mlp_gemm(const float* __restrict__ A, const float* __restrict__ A2,
                         const float* __restrict__ W, const float* __restrict__ bias,
                         float* __restrict__ C, int N)
{
    long long gid = (long long)blockIdx.x * blockDim.x + threadIdx.x;
    long long total = (long long)N * 32;
    if (gid >= total) return;
    int n = (int)(gid >> 5);
    int c4 = (int)(gid & 31);
    const float4* W4 = (const float4*)W;
    const float4* B4 = (const float4*)bias;
    float4 acc = B4[c4];
    const float* arow = A + (long long)n * K;
    const float* arow2 = A2 ? (A2 + (long long)n * K) : nullptr;
#pragma unroll 4
    for (int k = 0; k < K; ++k) {
        float a = arow[k];
        if (HASADD) a += arow2[k];
        float4 w = W4[k * 32 + c4];
        acc.x = fmaf(a, w.x, acc.x);
        acc.y = fmaf(a, w.y, acc.y);
        acc.z = fmaf(a, w.z, acc.z);
        acc.w = fmaf(a, w.w, acc.w);
    }
    if (RELU) {
        acc.x = fmaxf(acc.x, 0.f); acc.y = fmaxf(acc.y, 0.f);
        acc.z = fmaxf(acc.z, 0.f); acc.w = fmaxf(acc.w, 0.f);
    }
    ((float4*)C)[gid] = acc;
}

// ================= BN =================
__global__ void bn_stats(const float* __restrict__ h, float* __restrict__ sums, int N)
{
    __shared__ float ls[256], lq[256];
    int t = threadIdx.x;
    int c = t & 127, half = t >> 7;
    int nend = (blockIdx.x + 1) * 512;
    if (nend > N) nend = N;
    float s = 0.f, q = 0.f;
    for (int n = blockIdx.x * 512 + half; n < nend; n += 2) {
        float v = h[(long long)n * HID + c];
        s += v;
        q = fmaf(v, v, q);
    }
    ls[t] = s; lq[t] = q;
    __syncthreads();
    if (t < 128) {
        atomicAdd(&sums[c], ls[t] + ls[t + 128]);
        atomicAdd(&sums[128 + c], lq[t] + lq[t + 128]);
    }
}

__global__ void bn_finalize(const float* __restrict__ sums, const float* __restrict__ g,
                            const float* __restrict__ bt, float* __restrict__ ab, int N)
{
    int c = threadIdx.x;
    if (c < 128) {
        float inv = 1.f / (float)N;
        float mu = sums[c] * inv;
        float var = sums[128 + c] * inv - mu * mu;
        float rs = rsqrtf(fmaxf(var, 0.f) + 1e-5f);
        float a = g[c] * rs;
        ab[c] = a;
        ab[128 + c] = bt[c] - a * mu;
    }
}

__global__ void bn_apply_relu(const float* __restrict__ h, const float* __restrict__ ab,
                              float* __restrict__ out, long long total)
{
    long long i = (long long)blockIdx.x * blockDim.x + threadIdx.x;
    if (i >= total) return;
    int c = (int)(i & 127);
    float v = fmaf(h[i], ab[c], ab[128 + c]);
    out[i] = fmaxf(v, 0.f);
}

// ================= pool + head =================
__global__ void pool_scatter(const float* __restrict__ h, const int* __restrict__ batch,
                             float* __restrict__ pools, float* __restrict__ cnt, int N)
{
    long long i = (long long)blockIdx.x * blockDim.x + threadIdx.x;
    long long total = (long long)N * HID;
    if (i >= total) return;
    int n = (int)(i >> 7);
    int c = (int)(i & 127);
    int g = batch[n];
    atomicAdd(&pools[(long long)g * HID + c], h[i]);
    if (c == 0) atomicAdd(&cnt[g], 1.f);
}

__global__ void head_kernel(const float* __restrict__ pools, const float* __restrict__ cnt,
                            const float* __restrict__ Wf1, const float* __restrict__ bf1,
                            const float* __restrict__ Wf2, const float* __restrict__ bf2,
                            float* __restrict__ out, int G)
{
    int g = blockIdx.x;
    int t = threadIdx.x; // 64 threads = 1 wave
    __shared__ float p[128];
    float inv = 1.f / fmaxf(cnt[g], 1.f);
    p[t] = pools[g * 128 + t] * inv;
    p[t + 64] = pools[g * 128 + t + 64] * inv;
    __syncthreads();
    float o = bf1[t];
#pragma unroll 8
    for (int k = 0; k < 128; ++k) o = fmaf(p[k], Wf1[k * 64 + t], o);
    o = fmaxf(o, 0.f);
    float prod = o * Wf2[t];
#pragma unroll
    for (int off = 32; off > 0; off >>= 1) prod += __shfl_down(prod, off);
    if (t == 0) out[g] = prod + bf2[0];
}

extern "C" void kernel_launch(void* const* d_in, const int* in_sizes, int n_in,
                              void* d_out, int out_size, void* d_ws, size_t ws_size,
                              hipStream_t stream)
{
    const float* x     = (const float*)d_in[0];
    const float* ea    = (const float*)d_in[1];
    const int*   eidx  = (const int*)d_in[2];
    const int*   batch = (const int*)d_in[3];
    const float* We1 = (const float*)d_in[4];  const float* be1 = (const float*)d_in[5];
    const float* W11 = (const float*)d_in[6];  const float* b11 = (const float*)d_in[7];
    const float* W12 = (const float*)d_in[8];  const float* b12 = (const float*)d_in[9];
    const float* g1  = (const float*)d_in[10]; const float* bt1 = (const float*)d_in[11];
    const float* We2 = (const float*)d_in[12]; const float* be2 = (const float*)d_in[13];
    const float* W21 = (const float*)d_in[14]; const float* b21 = (const float*)d_in[15];
    const float* W22 = (const float*)d_in[16]; const float* b22 = (const float*)d_in[17];
    const float* g2  = (const float*)d_in[18]; const float* bt2 = (const float*)d_in[19];
    const float* We3 = (const float*)d_in[20]; const float* be3 = (const float*)d_in[21];
    const float* W31 = (const float*)d_in[22]; const float* b31 = (const float*)d_in[23];
    const float* W32 = (const float*)d_in[24]; const float* b32 = (const float*)d_in[25];
    const float* g3  = (const float*)d_in[26]; const float* bt3 = (const float*)d_in[27];
    const float* Wf1 = (const float*)d_in[28]; const float* bf1 = (const float*)d_in[29];
    const float* Wf2 = (const float*)d_in[30]; const float* bf2 = (const float*)d_in[31];

    const int N = in_sizes[0] / 7;
    const int E = in_sizes[1] / 3;
    const int G = out_size;
    const int* src = eidx;
    const int* dst = eidx + E;

    float* ws = (float*)d_ws;
    float* buf_h   = ws;                          // N*128
    float* buf_agg = buf_h + (size_t)N * HID;     // N*128
    float* buf_t   = buf_agg + (size_t)N * HID;   // N*128
    float* bnsums  = buf_t + (size_t)N * HID;     // 256
    float* bnab    = bnsums + 256;                // 256
    float* pools   = bnab + 256;                  // G*128
    float* cntp    = pools + (size_t)G * HID;     // G
    int*   icnt    = (int*)(cntp + G);            // N
    int*   ioffs   = icnt + N;                    // N+1
    int*   icur    = ioffs + N + 1;               // N
    int*   ielist  = icur + N;                    // E
    int*   ipart   = ielist + E;                  // 256
    int*   iexcl   = ipart + 256;                 // N

    const long long NH = (long long)N * HID;
    const int blk = 256;
    const unsigned grid_nh   = (unsigned)((NH + blk - 1) / blk);
    const unsigned grid_gemm = (unsigned)(((long long)N * 32 + blk - 1) / blk);
    const unsigned grid_bn   = (unsigned)((N + 511) / 512);
    const unsigned grid_E    = (unsigned)((E + blk - 1) / blk);
    const unsigned nb_scan   = (unsigned)((N + 255) / 256);
    const unsigned grid_gather  = (unsigned)((N + 3) / 4);    // 4 waves/block, 1 node/wave
    const unsigned grid_gat7 = (unsigned)(((long long)N * 8 + blk - 1) / blk);

    // ---------- build CSR (dst-grouped edge lists), once ----------
    hipMemsetAsync(icnt, 0, (size_t)N * sizeof(int), stream);
    hist_kernel<<<grid_E, blk, 0, stream>>>(dst, icnt, E);
    scan_block<<<nb_scan, 256, 0, stream>>>(icnt, iexcl, ipart, N);
    scan_partials<<<1, 256, 0, stream>>>(ipart, nb_scan, ioffs, N, E);
    scan_add<<<nb_scan, 256, 0, stream>>>(iexcl, ipart, ioffs, icur, N);
    fill_kernel<<<grid_E, blk, 0, stream>>>(dst, icur, ielist, E);

    // ---------- layer 1 ----------
    gather_d7<<<grid_gat7, blk, 0, stream>>>(x, ea, src, ioffs, ielist, We1, be1, buf_agg, N);
    mlp_gemm<7, true, true><<<grid_gemm, blk, 0, stream>>>(x, buf_agg, W11, b11, buf_t, N);
    mlp_gemm<128, false, false><<<grid_gemm, blk, 0, stream>>>(buf_t, nullptr, W12, b12, buf_agg, N);
    hipMemsetAsync(bnsums, 0, 256 * sizeof(float), stream);
    bn_stats<<<grid_bn, blk, 0, stream>>>(buf_agg, bnsums, N);
    bn_finalize<<<1, 128, 0, stream>>>(bnsums, g1, bt1, bnab, N);
    bn_apply_relu<<<grid_nh, blk, 0, stream>>>(buf_agg, bnab, buf_h, NH);

    // ---------- layer 2 ----------
    gather_d128<<<grid_gather, 256, 0, stream>>>(buf_h, ea, src, ioffs, ielist, We2, be2, buf_agg, N);
    mlp_gemm<128, true, true><<<grid_gemm, blk, 0, stream>>>(buf_h, buf_agg, W21, b21, buf_t, N);
    mlp_gemm<128, false, false><<<grid_gemm, blk, 0, stream>>>(buf_t, nullptr, W22, b22, buf_agg, N);
    hipMemsetAsync(bnsums, 0, 256 * sizeof(float), stream);
    bn_stats<<<grid_bn, blk, 0, stream>>>(buf_agg, bnsums, N);
    bn_finalize<<<1, 128, 0, stream>>>(bnsums, g2, bt2, bnab, N);
    bn_apply_relu<<<grid_nh, blk, 0, stream>>>(buf_agg, bnab, buf_h, NH);

    // ---------- layer 3 ----------
    gather_d128<<<grid_gather, 256, 0, stream>>>(buf_h, ea, src, ioffs, ielist, We3, be3, buf_agg, N);
    mlp_gemm<128, true, true><<<grid_gemm, blk, 0, stream>>>(buf_h, buf_agg, W31, b31, buf_t, N);
    mlp_gemm<128, false, false><<<grid_gemm, blk, 0, stream>>>(buf_t, nullptr, W32, b32, buf_agg, N);
    hipMemsetAsync(bnsums, 0, 256 * sizeof(float), stream);
    bn_stats<<<grid_bn, blk, 0, stream>>>(buf_agg, bnsums, N);
    bn_finalize<<<1, 128, 0, stream>>>(bnsums, g3, bt3, bnab, N);
    bn_apply_relu<<<grid_nh, blk, 0, stream>>>(buf_agg, bnab, buf_h, NH);

    // ---------- pool + head ----------
    hipMemsetAsync(pools, 0, ((size_t)G * HID + G) * sizeof(float), stream);
    pool_scatter<<<grid_nh, blk, 0, stream>>>(buf_h, batch, pools, cntp, N);
    head_kernel<<<G, 64, 0, stream>>>(pools, cntp, Wf1, bf1, Wf2, bf2, (float*)d_out, G);
}

// Round 4
// 981.890 us; speedup vs baseline: 2.0796x; 1.4250x over previous
//
#include <hip/hip_runtime.h>

#define HID 128

struct F4 { float v[4]; };

// ================= CSR build =================
__global__ void hist_kernel(const int* __restrict__ dst, int* __restrict__ cnt, int E)
{
    int e = blockIdx.x * blockDim.x + threadIdx.x;
    if (e < E) atomicAdd(&cnt[dst[e]], 1);
}

__global__ void scan_block(const int* __restrict__ cnt, int* __restrict__ excl,
                           int* __restrict__ partials, int Nn)
{
    __shared__ int ls[256];
    int i = blockIdx.x * 256 + threadIdx.x;
    int v = (i < Nn) ? cnt[i] : 0;
    ls[threadIdx.x] = v;
    __syncthreads();
    for (int off = 1; off < 256; off <<= 1) {
        int t = (threadIdx.x >= off) ? ls[threadIdx.x - off] : 0;
        __syncthreads();
        ls[threadIdx.x] += t;
        __syncthreads();
    }
    if (i < Nn) excl[i] = ls[threadIdx.x] - v;
    if (threadIdx.x == 255) partials[blockIdx.x] = ls[255];
}

__global__ void scan_partials(int* __restrict__ partials, int nb, int* __restrict__ offsets,
                              int Nn, int E)
{
    __shared__ int ls[256];
    int t = threadIdx.x;
    int v = (t < nb) ? partials[t] : 0;
    ls[t] = v;
    __syncthreads();
    for (int off = 1; off < 256; off <<= 1) {
        int x = (t >= off) ? ls[t - off] : 0;
        __syncthreads();
        ls[t] += x;
        __syncthreads();
    }
    if (t < nb) partials[t] = ls[t] - v;
    if (t == 0) offsets[Nn] = E;
}

__global__ void scan_add(const int* __restrict__ excl, const int* __restrict__ partials,
                         int* __restrict__ offsets, int* __restrict__ cursor, int Nn)
{
    int i = blockIdx.x * 256 + threadIdx.x;
    if (i < Nn) {
        int o = excl[i] + partials[blockIdx.x];
        offsets[i] = o;
        cursor[i] = o;
    }
}

__global__ void fill_kernel(const int* __restrict__ dst, int* __restrict__ cursor,
                            int* __restrict__ elist, int E)
{
    int e = blockIdx.x * blockDim.x + threadIdx.x;
    if (e < E) {
        int pos = atomicAdd(&cursor[dst[e]], 1);
        elist[pos] = e;
    }
}

// ================= layer 1: CSR gather (dim 7) =================
__global__ void gather_d7(const float* __restrict__ x, const float* __restrict__ ea,
                          const int* __restrict__ srcArr,
                          const int* __restrict__ offsets, const int* __restrict__ elist,
                          const float* __restrict__ We, const float* __restrict__ be,
                          float* __restrict__ agg, int Nn)
{
    int tid = blockIdx.x * blockDim.x + threadIdx.x;
    int node = tid >> 3;
    int c = tid & 7;
    if (node >= Nn) return;
    float w0 = 0.f, w1 = 0.f, w2 = 0.f, b = 0.f;
    if (c < 7) { w0 = We[c]; w1 = We[7 + c]; w2 = We[14 + c]; b = be[c]; }
    int beg = offsets[node], end = offsets[node + 1];
    float acc = 0.f;
    for (int i = beg; i < end; ++i) {
        int e = elist[i];
        int s = srcArr[e];
        float a0 = ea[e * 3], a1 = ea[e * 3 + 1], a2 = ea[e * 3 + 2];
        float v = b;
        v = fmaf(a0, w0, v);
        v = fmaf(a1, w1, v);
        v = fmaf(a2, w2, v);
        if (c < 7) v += x[s * 7 + c];
        acc += fmaxf(v, 0.f);
    }
    if (c < 7) agg[node * 7 + c] = acc;
}

// ================= layers 2/3: CSR gather-aggregate (dim 128) =================
__global__ void gather_d128(const float* __restrict__ h, const float* __restrict__ ea,
                            const int* __restrict__ srcArr,
                            const int* __restrict__ offsets, const int* __restrict__ elist,
                            const float* __restrict__ We, const float* __restrict__ be,
                            float* __restrict__ agg, int Nn)
{
    int node = blockIdx.x * (blockDim.x >> 6) + (threadIdx.x >> 6);
    if (node >= Nn) return;
    int lane = threadIdx.x & 63;
    int beg = offsets[node], end = offsets[node + 1];
    const float2* W2 = (const float2*)We;
    float2 w0 = W2[lane];
    float2 w1 = W2[64 + lane];
    float2 w2 = W2[128 + lane];
    float2 bb = ((const float2*)be)[lane];
    float accx = 0.f, accy = 0.f;

    int e = 0, s = 0;
    float a0 = 0.f, a1 = 0.f, a2 = 0.f;
    if (beg < end) {
        e = elist[beg]; s = srcArr[e];
        a0 = ea[e * 3]; a1 = ea[e * 3 + 1]; a2 = ea[e * 3 + 2];
    }
    for (int i = beg; i < end; ++i) {
        float2 hv = ((const float2*)(h + (size_t)s * HID))[lane];
        float ca0 = a0, ca1 = a1, ca2 = a2;
        if (i + 1 < end) {
            int e2 = elist[i + 1];
            s = srcArr[e2];
            a0 = ea[e2 * 3]; a1 = ea[e2 * 3 + 1]; a2 = ea[e2 * 3 + 2];
        }
        float vx = bb.x + hv.x;
        vx = fmaf(ca0, w0.x, vx); vx = fmaf(ca1, w1.x, vx); vx = fmaf(ca2, w2.x, vx);
        float vy = bb.y + hv.y;
        vy = fmaf(ca0, w0.y, vy); vy = fmaf(ca1, w1.y, vy); vy = fmaf(ca2, w2.y, vy);
        accx += fmaxf(vx, 0.f);
        accy += fmaxf(vy, 0.f);
    }
    float2 outv = {accx, accy};
    ((float2*)(agg + (size_t)node * HID))[lane] = outv;
}

// ================= tiled fp32 GEMM: C[N,128] = op((A(+A2)) @ W[128,128] + b) =======
// block: 256 threads -> 64 nodes x 128 cols; thread: 4 nodes x 8 cols
template <bool HASADD, bool RELU>
__global__ __launch_bounds__(256) void gemm128_tiled(const float* __restrict__ A,
                                                     const float* __restrict__ A2,
                                                     const float* __restrict__ W,
                                                     const float* __restrict__ bias,
                                                     float* __restrict__ C, int N)
{
    __shared__ float As[64 * 128];
    int t = threadIdx.x;
    int nb = blockIdx.x * 64;
    // stage A (+A2): 2048 float4s, 8 per thread, coalesced
    {
        const float4* A4 = (const float4*)(A + (size_t)nb * HID);
        const float4* B4 = (const float4*)(HASADD ? (A2 + (size_t)nb * HID) : nullptr);
        int limit4 = 32 * (N - nb < 64 ? (N - nb) : 64);
#pragma unroll
        for (int i = 0; i < 8; ++i) {
            int idx = t + i * 256;
            float4 v = {0.f, 0.f, 0.f, 0.f};
            if (idx < limit4) {
                v = A4[idx];
                if (HASADD) {
                    float4 u = B4[idx];
                    v.x += u.x; v.y += u.y; v.z += u.z; v.w += u.w;
                }
            }
            ((float4*)As)[idx] = v;
        }
    }
    __syncthreads();

    int c8 = t & 15;   // cols 8*c8 .. 8*c8+7
    int ng = t >> 4;   // nodes ng*4 .. ng*4+3
    const float4* W4 = (const float4*)W;
    float4 acc[4][2];
    {
        const float4* Bb = (const float4*)bias;
        float4 b0 = Bb[c8 * 2], b1 = Bb[c8 * 2 + 1];
#pragma unroll
        for (int j = 0; j < 4; ++j) { acc[j][0] = b0; acc[j][1] = b1; }
    }
    const float* As0 = As + ng * 4 * HID;
#pragma unroll 4
    for (int k = 0; k < HID; k += 4) {
        F4 a[4];
#pragma unroll
        for (int j = 0; j < 4; ++j) a[j] = *(const F4*)(As0 + j * HID + k);
#pragma unroll
        for (int kk = 0; kk < 4; ++kk) {
            float4 w0 = W4[(k + kk) * 32 + c8 * 2];
            float4 w1 = W4[(k + kk) * 32 + c8 * 2 + 1];
#pragma unroll
            for (int j = 0; j < 4; ++j) {
                float av = a[j].v[kk];
                acc[j][0].x = fmaf(av, w0.x, acc[j][0].x);
                acc[j][0].y = fmaf(av, w0.y, acc[j][0].y);
                acc[j][0].z = fmaf(av, w0.z, acc[j][0].z);
                acc[j][0].w = fmaf(av, w0.w, acc[j][0].w);
                acc[j][1].x = fmaf(av, w1.x, acc[j][1].x);
                acc[j][1].y = fmaf(av, w1.y, acc[j][1].y);
                acc[j][1].z = fmaf(av, w1.z, acc[j][1].z);
                acc[j][1].w = fmaf(av, w1.w, acc[j][1].w);
            }
        }
    }
#pragma unroll
    for (int j = 0; j < 4; ++j) {
        int n = nb + ng * 4 + j;
        if (n >= N) break;
        float4 o0 = acc[j][0], o1 = acc[j][1];
        if (RELU) {
            o0.x = fmaxf(o0.x, 0.f); o0.y = fmaxf(o0.y, 0.f);
            o0.z = fmaxf(o0.z, 0.f); o0.w = fmaxf(o0.w, 0.f);
            o1.x = fmaxf(o1.x, 0.f); o1.y = fmaxf(o1.y, 0.f);
            o1.z = fmaxf(o1.z, 0.f); o1.w = fmaxf(o1.w, 0.f);
        }
        float4* Cp = (float4*)(C + (size_t)n * HID) + c8 * 2;
        Cp[0] = o0;
        Cp[1] = o1;
    }
}

// ================= small GEMM for layer-1 (K=7) =================
template <int K, bool HASADD, bool RELU>
__global__ void mlp_gemm(const float* __restrict__ A, const float* __restrict__ A2,
                         const float* __restrict__ W, const float* __restrict__ bias,
                         float* __restrict__ C, int N)
{
    long long gid = (long long)blockIdx.x * blockDim.x + threadIdx.x;
    long long total = (long long)N * 32;
    if (gid >= total) return;
    int n = (int)(gid >> 5);
    int c4 = (int)(gid & 31);
    const float4* W4 = (const float4*)W;
    const float4* B4 = (const float4*)bias;
    float4 acc = B4[c4];
    const float* arow = A + (long long)n * K;
    const float* arow2 = A2 ? (A2 + (long long)n * K) : nullptr;
#pragma unroll 4
    for (int k = 0; k < K; ++k) {
        float a = arow[k];
        if (HASADD) a += arow2[k];
        float4 w = W4[k * 32 + c4];
        acc.x = fmaf(a, w.x, acc.x);
        acc.y = fmaf(a, w.y, acc.y);
        acc.z = fmaf(a, w.z, acc.z);
        acc.w = fmaf(a, w.w, acc.w);
    }
    if (RELU) {
        acc.x = fmaxf(acc.x, 0.f); acc.y = fmaxf(acc.y, 0.f);
        acc.z = fmaxf(acc.z, 0.f); acc.w = fmaxf(acc.w, 0.f);
    }
    ((float4*)C)[gid] = acc;
}

// ================= BN =================
__global__ void bn_stats(const float* __restrict__ h, float* __restrict__ sums, int N)
{
    __shared__ float ls[256], lq[256];
    int t = threadIdx.x;
    int c = t & 127, half = t >> 7;
    int nend = (blockIdx.x + 1) * 512;
    if (nend > N) nend = N;
    float s = 0.f, q = 0.f;
    for (int n = blockIdx.x * 512 + half; n < nend; n += 2) {
        float v = h[(long long)n * HID + c];
        s += v;
        q = fmaf(v, v, q);
    }
    ls[t] = s; lq[t] = q;
    __syncthreads();
    if (t < 128) {
        atomicAdd(&sums[c], ls[t] + ls[t + 128]);
        atomicAdd(&sums[128 + c], lq[t] + lq[t + 128]);
    }
}

__global__ void bn_finalize(const float* __restrict__ sums, const float* __restrict__ g,
                            const float* __restrict__ bt, float* __restrict__ ab, int N)
{
    int c = threadIdx.x;
    if (c < 128) {
        float inv = 1.f / (float)N;
        float mu = sums[c] * inv;
        float var = sums[128 + c] * inv - mu * mu;
        float rs = rsqrtf(fmaxf(var, 0.f) + 1e-5f);
        float a = g[c] * rs;
        ab[c] = a;
        ab[128 + c] = bt[c] - a * mu;
    }
}

__global__ void bn_apply_relu(const float* __restrict__ h, const float* __restrict__ ab,
                              float* __restrict__ out, long long total)
{
    long long i = (long long)blockIdx.x * blockDim.x + threadIdx.x;
    if (i >= total) return;
    int c = (int)(i & 127);
    float v = fmaf(h[i], ab[c], ab[128 + c]);
    out[i] = fmaxf(v, 0.f);
}

// ================= pool + head =================
__global__ void pool_scatter(const float* __restrict__ h, const int* __restrict__ batch,
                             float* __restrict__ pools, float* __restrict__ cnt, int N)
{
    long long i = (long long)blockIdx.x * blockDim.x + threadIdx.x;
    long long total = (long long)N * HID;
    if (i >= total) return;
    int n = (int)(i >> 7);
    int c = (int)(i & 127);
    int g = batch[n];
    atomicAdd(&pools[(long long)g * HID + c], h[i]);
    if (c == 0) atomicAdd(&cnt[g], 1.f);
}

__global__ void head_kernel(const float* __restrict__ pools, const float* __restrict__ cnt,
                            const float* __restrict__ Wf1, const float* __restrict__ bf1,
                            const float* __restrict__ Wf2, const float* __restrict__ bf2,
                            float* __restrict__ out, int G)
{
    int g = blockIdx.x;
    int t = threadIdx.x;
    __shared__ float p[128];
    float inv = 1.f / fmaxf(cnt[g], 1.f);
    p[t] = pools[g * 128 + t] * inv;
    p[t + 64] = pools[g * 128 + t + 64] * inv;
    __syncthreads();
    float o = bf1[t];
#pragma unroll 8
    for (int k = 0; k < 128; ++k) o = fmaf(p[k], Wf1[k * 64 + t], o);
    o = fmaxf(o, 0.f);
    float prod = o * Wf2[t];
#pragma unroll
    for (int off = 32; off > 0; off >>= 1) prod += __shfl_down(prod, off);
    if (t == 0) out[g] = prod + bf2[0];
}

extern "C" void kernel_launch(void* const* d_in, const int* in_sizes, int n_in,
                              void* d_out, int out_size, void* d_ws, size_t ws_size,
                              hipStream_t stream)
{
    const float* x     = (const float*)d_in[0];
    const float* ea    = (const float*)d_in[1];
    const int*   eidx  = (const int*)d_in[2];
    const int*   batch = (const int*)d_in[3];
    const float* We1 = (const float*)d_in[4];  const float* be1 = (const float*)d_in[5];
    const float* W11 = (const float*)d_in[6];  const float* b11 = (const float*)d_in[7];
    const float* W12 = (const float*)d_in[8];  const float* b12 = (const float*)d_in[9];
    const float* g1  = (const float*)d_in[10]; const float* bt1 = (const float*)d_in[11];
    const float* We2 = (const float*)d_in[12]; const float* be2 = (const float*)d_in[13];
    const float* W21 = (const float*)d_in[14]; const float* b21 = (const float*)d_in[15];
    const float* W22 = (const float*)d_in[16]; const float* b22 = (const float*)d_in[17];
    const float* g2  = (const float*)d_in[18]; const float* bt2 = (const float*)d_in[19];
    const float* We3 = (const float*)d_in[20]; const float* be3 = (const float*)d_in[21];
    const float* W31 = (const float*)d_in[22]; const float* b31 = (const float*)d_in[23];
    const float* W32 = (const float*)d_in[24]; const float* b32 = (const float*)d_in[25];
    const float* g3  = (const float*)d_in[26]; const float* bt3 = (const float*)d_in[27];
    const float* Wf1 = (const float*)d_in[28]; const float* bf1 = (const float*)d_in[29];
    const float* Wf2 = (const float*)d_in[30]; const float* bf2 = (const float*)d_in[31];

    const int N = in_sizes[0] / 7;
    const int E = in_sizes[1] / 3;
    const int G = out_size;
    const int* src = eidx;
    const int* dst = eidx + E;

    float* ws = (float*)d_ws;
    float* buf_h   = ws;                          // N*128
    float* buf_agg = buf_h + (size_t)N * HID;     // N*128
    float* buf_t   = buf_agg + (size_t)N * HID;   // N*128
    float* bnsums  = buf_t + (size_t)N * HID;     // 256
    float* bnab    = bnsums + 256;                // 256
    float* pools   = bnab + 256;                  // G*128
    float* cntp    = pools + (size_t)G * HID;     // G
    int*   icnt    = (int*)(cntp + G);            // N
    int*   ioffs   = icnt + N;                    // N+1
    int*   icur    = ioffs + N + 1;               // N
    int*   ielist  = icur + N;                    // E
    int*   ipart   = ielist + E;                  // 256
    int*   iexcl   = ipart + 256;                 // N

    const long long NH = (long long)N * HID;
    const int blk = 256;
    const unsigned grid_nh   = (unsigned)((NH + blk - 1) / blk);
    const unsigned grid_gemm = (unsigned)(((long long)N * 32 + blk - 1) / blk);
    const unsigned grid_tile = (unsigned)((N + 63) / 64);
    const unsigned grid_bn   = (unsigned)((N + 511) / 512);
    const unsigned grid_E    = (unsigned)((E + blk - 1) / blk);
    const unsigned nb_scan   = (unsigned)((N + 255) / 256);
    const unsigned grid_gather = (unsigned)((N + 3) / 4);
    const unsigned grid_gat7 = (unsigned)(((long long)N * 8 + blk - 1) / blk);

    // ---------- build CSR ----------
    hipMemsetAsync(icnt, 0, (size_t)N * sizeof(int), stream);
    hist_kernel<<<grid_E, blk, 0, stream>>>(dst, icnt, E);
    scan_block<<<nb_scan, 256, 0, stream>>>(icnt, iexcl, ipart, N);
    scan_partials<<<1, 256, 0, stream>>>(ipart, nb_scan, ioffs, N, E);
    scan_add<<<nb_scan, 256, 0, stream>>>(iexcl, ipart, ioffs, icur, N);
    fill_kernel<<<grid_E, blk, 0, stream>>>(dst, icur, ielist, E);

    // ---------- layer 1 ----------
    gather_d7<<<grid_gat7, blk, 0, stream>>>(x, ea, src, ioffs, ielist, We1, be1, buf_agg, N);
    mlp_gemm<7, true, true><<<grid_gemm, blk, 0, stream>>>(x, buf_agg, W11, b11, buf_t, N);
    gemm128_tiled<false, false><<<grid_tile, 256, 0, stream>>>(buf_t, nullptr, W12, b12, buf_agg, N);
    hipMemsetAsync(bnsums, 0, 256 * sizeof(float), stream);
    bn_stats<<<grid_bn, blk, 0, stream>>>(buf_agg, bnsums, N);
    bn_finalize<<<1, 128, 0, stream>>>(bnsums, g1, bt1, bnab, N);
    bn_apply_relu<<<grid_nh, blk, 0, stream>>>(buf_agg, bnab, buf_h, NH);

    // ---------- layer 2 ----------
    gather_d128<<<grid_gather, 256, 0, stream>>>(buf_h, ea, src, ioffs, ielist, We2, be2, buf_agg, N);
    gemm128_tiled<true, true><<<grid_tile, 256, 0, stream>>>(buf_h, buf_agg, W21, b21, buf_t, N);
    gemm128_tiled<false, false><<<grid_tile, 256, 0, stream>>>(buf_t, nullptr, W22, b22, buf_agg, N);
    hipMemsetAsync(bnsums, 0, 256 * sizeof(float), stream);
    bn_stats<<<grid_bn, blk, 0, stream>>>(buf_agg, bnsums, N);
    bn_finalize<<<1, 128, 0, stream>>>(bnsums, g2, bt2, bnab, N);
    bn_apply_relu<<<grid_nh, blk, 0, stream>>>(buf_agg, bnab, buf_h, NH);

    // ---------- layer 3 ----------
    gather_d128<<<grid_gather, 256, 0, stream>>>(buf_h, ea, src, ioffs, ielist, We3, be3, buf_agg, N);
    gemm128_tiled<true, true><<<grid_tile, 256, 0, stream>>>(buf_h, buf_agg, W31, b31, buf_t, N);
    gemm128_tiled<false, false><<<grid_tile, 256, 0, stream>>>(buf_t, nullptr, W32, b32, buf_agg, N);
    hipMemsetAsync(bnsums, 0, 256 * sizeof(float), stream);
    bn_stats<<<grid_bn, blk, 0, stream>>>(buf_agg, bnsums, N);
    bn_finalize<<<1, 128, 0, stream>>>(bnsums, g3, bt3, bnab, N);
    bn_apply_relu<<<grid_nh, blk, 0, stream>>>(buf_agg, bnab, buf_h, NH);

    // ---------- pool + head ----------
    hipMemsetAsync(pools, 0, ((size_t)G * HID + G) * sizeof(float), stream);
    pool_scatter<<<grid_nh, blk, 0, stream>>>(buf_h, batch, pools, cntp, N);
    head_kernel<<<G, 64, 0, stream>>>(pools, cntp, Wf1, bf1, Wf2, bf2, (float*)d_out, G);
}

// Round 5
// 913.555 us; speedup vs baseline: 2.2352x; 1.0748x over previous
//
#include <hip/hip_runtime.h>

#define HID 128

struct F4 { float v[4]; };

__device__ inline unsigned short f2bf(float f) {
    unsigned u = __float_as_uint(f);
    unsigned r = (u + 0x7fff + ((u >> 16) & 1)) >> 16;
    return (unsigned short)r;
}
__device__ inline float bf2f(unsigned short b) {
    return __uint_as_float(((unsigned)b) << 16);
}

// ================= CSR build =================
__global__ void hist_kernel(const int* __restrict__ dst, int* __restrict__ cnt, int E)
{
    int e = blockIdx.x * blockDim.x + threadIdx.x;
    if (e < E) atomicAdd(&cnt[dst[e]], 1);
}

__global__ void scan_block(const int* __restrict__ cnt, int* __restrict__ excl,
                           int* __restrict__ partials, int Nn)
{
    __shared__ int ls[256];
    int i = blockIdx.x * 256 + threadIdx.x;
    int v = (i < Nn) ? cnt[i] : 0;
    ls[threadIdx.x] = v;
    __syncthreads();
    for (int off = 1; off < 256; off <<= 1) {
        int t = (threadIdx.x >= off) ? ls[threadIdx.x - off] : 0;
        __syncthreads();
        ls[threadIdx.x] += t;
        __syncthreads();
    }
    if (i < Nn) excl[i] = ls[threadIdx.x] - v;
    if (threadIdx.x == 255) partials[blockIdx.x] = ls[255];
}

__global__ void scan_partials(int* __restrict__ partials, int nb, int* __restrict__ offsets,
                              int Nn, int E)
{
    __shared__ int ls[256];
    int t = threadIdx.x;
    int v = (t < nb) ? partials[t] : 0;
    ls[t] = v;
    __syncthreads();
    for (int off = 1; off < 256; off <<= 1) {
        int x = (t >= off) ? ls[t - off] : 0;
        __syncthreads();
        ls[t] += x;
        __syncthreads();
    }
    if (t < nb) partials[t] = ls[t] - v;
    if (t == 0) offsets[Nn] = E;
}

__global__ void scan_add(const int* __restrict__ excl, const int* __restrict__ partials,
                         int* __restrict__ offsets, int* __restrict__ cursor, int Nn)
{
    int i = blockIdx.x * 256 + threadIdx.x;
    if (i < Nn) {
        int o = excl[i] + partials[blockIdx.x];
        offsets[i] = o;
        cursor[i] = o;
    }
}

// fill CSR with packed edge records: {src_as_float_bits, ea0, ea1, ea2}
__global__ void fill_kernel(const int* __restrict__ dst, const int* __restrict__ src,
                            const float* __restrict__ ea, int* __restrict__ cursor,
                            float4* __restrict__ epack, int E)
{
    int e = blockIdx.x * blockDim.x + threadIdx.x;
    if (e < E) {
        int pos = atomicAdd(&cursor[dst[e]], 1);
        float4 p;
        p.x = __int_as_float(src[e]);
        p.y = ea[e * 3];
        p.z = ea[e * 3 + 1];
        p.w = ea[e * 3 + 2];
        epack[pos] = p;
    }
}

// ================= layer 1: CSR gather (dim 7) =================
__global__ void gather_d7(const float* __restrict__ x, const float4* __restrict__ epack,
                          const int* __restrict__ offsets,
                          const float* __restrict__ We, const float* __restrict__ be,
                          float* __restrict__ agg, int Nn)
{
    int tid = blockIdx.x * blockDim.x + threadIdx.x;
    int node = tid >> 3;
    int c = tid & 7;
    if (node >= Nn) return;
    float w0 = 0.f, w1 = 0.f, w2 = 0.f, b = 0.f;
    if (c < 7) { w0 = We[c]; w1 = We[7 + c]; w2 = We[14 + c]; b = be[c]; }
    int beg = offsets[node], end = offsets[node + 1];
    float acc = 0.f;
    for (int i = beg; i < end; ++i) {
        float4 ep = epack[i];
        int s = __float_as_int(ep.x);
        float v = b;
        v = fmaf(ep.y, w0, v);
        v = fmaf(ep.z, w1, v);
        v = fmaf(ep.w, w2, v);
        if (c < 7) v += x[s * 7 + c];
        acc += fmaxf(v, 0.f);
    }
    if (c < 7) agg[node * 7 + c] = acc;
}

// ================= layers 2/3: CSR gather-aggregate, bf16 h =================
__global__ void gather_d128(const unsigned short* __restrict__ h16,
                            const float4* __restrict__ epack,
                            const int* __restrict__ offsets,
                            const float* __restrict__ We, const float* __restrict__ be,
                            float* __restrict__ agg, int Nn)
{
    int node = blockIdx.x * (blockDim.x >> 6) + (threadIdx.x >> 6);
    if (node >= Nn) return;
    int lane = threadIdx.x & 63;
    int beg = offsets[node], end = offsets[node + 1];
    const float2* W2 = (const float2*)We;
    float2 w0 = W2[lane];
    float2 w1 = W2[64 + lane];
    float2 w2 = W2[128 + lane];
    float2 bb = ((const float2*)be)[lane];
    float accx = 0.f, accy = 0.f;

    float4 ep;
    if (beg < end) ep = epack[beg];
    for (int i = beg; i < end; ++i) {
        float4 cur = ep;
        if (i + 1 < end) ep = epack[i + 1];
        int s = __float_as_int(cur.x);
        ushort2 hp = ((const ushort2*)(h16 + (size_t)s * HID))[lane];
        float hx = bf2f(hp.x), hy = bf2f(hp.y);
        float vx = bb.x + hx;
        vx = fmaf(cur.y, w0.x, vx); vx = fmaf(cur.z, w1.x, vx); vx = fmaf(cur.w, w2.x, vx);
        float vy = bb.y + hy;
        vy = fmaf(cur.y, w0.y, vy); vy = fmaf(cur.z, w1.y, vy); vy = fmaf(cur.w, w2.y, vy);
        accx += fmaxf(vx, 0.f);
        accy += fmaxf(vy, 0.f);
    }
    float2 outv = {accx, accy};
    ((float2*)(agg + (size_t)node * HID))[lane] = outv;
}

// ================= tiled fp32 GEMM =================
template <bool HASADD, bool RELU>
__global__ __launch_bounds__(256) void gemm128_tiled(const float* __restrict__ A,
                                                     const float* __restrict__ A2,
                                                     const float* __restrict__ W,
                                                     const float* __restrict__ bias,
                                                     float* __restrict__ C, int N)
{
    __shared__ float As[64 * 128];
    int t = threadIdx.x;
    int nb = blockIdx.x * 64;
    {
        const float4* A4 = (const float4*)(A + (size_t)nb * HID);
        const float4* B4 = (const float4*)(HASADD ? (A2 + (size_t)nb * HID) : nullptr);
        int limit4 = 32 * (N - nb < 64 ? (N - nb) : 64);
#pragma unroll
        for (int i = 0; i < 8; ++i) {
            int idx = t + i * 256;
            float4 v = {0.f, 0.f, 0.f, 0.f};
            if (idx < limit4) {
                v = A4[idx];
                if (HASADD) {
                    float4 u = B4[idx];
                    v.x += u.x; v.y += u.y; v.z += u.z; v.w += u.w;
                }
            }
            ((float4*)As)[idx] = v;
        }
    }
    __syncthreads();

    int c8 = t & 15;
    int ng = t >> 4;
    const float4* W4 = (const float4*)W;
    float4 acc[4][2];
    {
        const float4* Bb = (const float4*)bias;
        float4 b0 = Bb[c8 * 2], b1 = Bb[c8 * 2 + 1];
#pragma unroll
        for (int j = 0; j < 4; ++j) { acc[j][0] = b0; acc[j][1] = b1; }
    }
    const float* As0 = As + ng * 4 * HID;
#pragma unroll 4
    for (int k = 0; k < HID; k += 4) {
        F4 a[4];
#pragma unroll
        for (int j = 0; j < 4; ++j) a[j] = *(const F4*)(As0 + j * HID + k);
#pragma unroll
        for (int kk = 0; kk < 4; ++kk) {
            float4 w0 = W4[(k + kk) * 32 + c8 * 2];
            float4 w1 = W4[(k + kk) * 32 + c8 * 2 + 1];
#pragma unroll
            for (int j = 0; j < 4; ++j) {
                float av = a[j].v[kk];
                acc[j][0].x = fmaf(av, w0.x, acc[j][0].x);
                acc[j][0].y = fmaf(av, w0.y, acc[j][0].y);
                acc[j][0].z = fmaf(av, w0.z, acc[j][0].z);
                acc[j][0].w = fmaf(av, w0.w, acc[j][0].w);
                acc[j][1].x = fmaf(av, w1.x, acc[j][1].x);
                acc[j][1].y = fmaf(av, w1.y, acc[j][1].y);
                acc[j][1].z = fmaf(av, w1.z, acc[j][1].z);
                acc[j][1].w = fmaf(av, w1.w, acc[j][1].w);
            }
        }
    }
#pragma unroll
    for (int j = 0; j < 4; ++j) {
        int n = nb + ng * 4 + j;
        if (n >= N) break;
        float4 o0 = acc[j][0], o1 = acc[j][1];
        if (RELU) {
            o0.x = fmaxf(o0.x, 0.f); o0.y = fmaxf(o0.y, 0.f);
            o0.z = fmaxf(o0.z, 0.f); o0.w = fmaxf(o0.w, 0.f);
            o1.x = fmaxf(o1.x, 0.f); o1.y = fmaxf(o1.y, 0.f);
            o1.z = fmaxf(o1.z, 0.f); o1.w = fmaxf(o1.w, 0.f);
        }
        float4* Cp = (float4*)(C + (size_t)n * HID) + c8 * 2;
        Cp[0] = o0;
        Cp[1] = o1;
    }
}

// ================= small GEMM for layer-1 (K=7) =================
template <int K, bool HASADD, bool RELU>
__global__ void mlp_gemm(const float* __restrict__ A, const float* __restrict__ A2,
                         const float* __restrict__ W, const float* __restrict__ bias,
                         float* __restrict__ C, int N)
{
    long long gid = (long long)blockIdx.x * blockDim.x + threadIdx.x;
    long long total = (long long)N * 32;
    if (gid >= total) return;
    int n = (int)(gid >> 5);
    int c4 = (int)(gid & 31);
    const float4* W4 = (const float4*)W;
    const float4* B4 = (const float4*)bias;
    float4 acc = B4[c4];
    const float* arow = A + (long long)n * K;
    const float* arow2 = A2 ? (A2 + (long long)n * K) : nullptr;
#pragma unroll 4
    for (int k = 0; k < K; ++k) {
        float a = arow[k];
        if (HASADD) a += arow2[k];
        float4 w = W4[k * 32 + c4];
        acc.x = fmaf(a, w.x, acc.x);
        acc.y = fmaf(a, w.y, acc.y);
        acc.z = fmaf(a, w.z, acc.z);
        acc.w = fmaf(a, w.w, acc.w);
    }
    if (RELU) {
        acc.x = fmaxf(acc.x, 0.f); acc.y = fmaxf(acc.y, 0.f);
        acc.z = fmaxf(acc.z, 0.f); acc.w = fmaxf(acc.w, 0.f);
    }
    ((float4*)C)[gid] = acc;
}

// ================= BN =================
__global__ void bn_stats(const float* __restrict__ h, float* __restrict__ sums, int N)
{
    __shared__ float ls[256], lq[256];
    int t = threadIdx.x;
    int c = t & 127, half = t >> 7;
    int nend = (blockIdx.x + 1) * 512;
    if (nend > N) nend = N;
    float s = 0.f, q = 0.f;
    for (int n = blockIdx.x * 512 + half; n < nend; n += 2) {
        float v = h[(long long)n * HID + c];
        s += v;
        q = fmaf(v, v, q);
    }
    ls[t] = s; lq[t] = q;
    __syncthreads();
    if (t < 128) {
        atomicAdd(&sums[c], ls[t] + ls[t + 128]);
        atomicAdd(&sums[128 + c], lq[t] + lq[t + 128]);
    }
}

__global__ void bn_finalize(const float* __restrict__ sums, const float* __restrict__ g,
                            const float* __restrict__ bt, float* __restrict__ ab, int N)
{
    int c = threadIdx.x;
    if (c < 128) {
        float inv = 1.f / (float)N;
        float mu = sums[c] * inv;
        float var = sums[128 + c] * inv - mu * mu;
        float rs = rsqrtf(fmaxf(var, 0.f) + 1e-5f);
        float a = g[c] * rs;
        ab[c] = a;
        ab[128 + c] = bt[c] - a * mu;
    }
}

// 2 elements per thread; optionally emits bf16 mirror for the gather
template <bool W16>
__global__ void bn_apply_relu(const float* __restrict__ h, const float* __restrict__ ab,
                              float* __restrict__ out, unsigned short* __restrict__ h16,
                              long long total)
{
    long long i = ((long long)blockIdx.x * blockDim.x + threadIdx.x) * 2;
    if (i >= total) return;
    int c = (int)(i & 127);
    float2 hv = *(const float2*)(h + i);
    float v0 = fmaxf(fmaf(hv.x, ab[c], ab[128 + c]), 0.f);
    float v1 = fmaxf(fmaf(hv.y, ab[c + 1], ab[129 + c]), 0.f);
    float2 ov = {v0, v1};
    *(float2*)(out + i) = ov;
    if (W16) {
        unsigned pair = (unsigned)f2bf(v0) | ((unsigned)f2bf(v1) << 16);
        *(unsigned*)(h16 + i) = pair;
    }
}

// ================= pool + head =================
__global__ void pool_scatter(const float* __restrict__ h, const int* __restrict__ batch,
                             float* __restrict__ pools, float* __restrict__ cnt, int N)
{
    long long i = (long long)blockIdx.x * blockDim.x + threadIdx.x;
    long long total = (long long)N * HID;
    if (i >= total) return;
    int n = (int)(i >> 7);
    int c = (int)(i & 127);
    int g = batch[n];
    atomicAdd(&pools[(long long)g * HID + c], h[i]);
    if (c == 0) atomicAdd(&cnt[g], 1.f);
}

__global__ void head_kernel(const float* __restrict__ pools, const float* __restrict__ cnt,
                            const float* __restrict__ Wf1, const float* __restrict__ bf1,
                            const float* __restrict__ Wf2, const float* __restrict__ bf2,
                            float* __restrict__ out, int G)
{
    int g = blockIdx.x;
    int t = threadIdx.x;
    __shared__ float p[128];
    float inv = 1.f / fmaxf(cnt[g], 1.f);
    p[t] = pools[g * 128 + t] * inv;
    p[t + 64] = pools[g * 128 + t + 64] * inv;
    __syncthreads();
    float o = bf1[t];
#pragma unroll 8
    for (int k = 0; k < 128; ++k) o = fmaf(p[k], Wf1[k * 64 + t], o);
    o = fmaxf(o, 0.f);
    float prod = o * Wf2[t];
#pragma unroll
    for (int off = 32; off > 0; off >>= 1) prod += __shfl_down(prod, off);
    if (t == 0) out[g] = prod + bf2[0];
}

extern "C" void kernel_launch(void* const* d_in, const int* in_sizes, int n_in,
                              void* d_out, int out_size, void* d_ws, size_t ws_size,
                              hipStream_t stream)
{
    const float* x     = (const float*)d_in[0];
    const float* ea    = (const float*)d_in[1];
    const int*   eidx  = (const int*)d_in[2];
    const int*   batch = (const int*)d_in[3];
    const float* We1 = (const float*)d_in[4];  const float* be1 = (const float*)d_in[5];
    const float* W11 = (const float*)d_in[6];  const float* b11 = (const float*)d_in[7];
    const float* W12 = (const float*)d_in[8];  const float* b12 = (const float*)d_in[9];
    const float* g1  = (const float*)d_in[10]; const float* bt1 = (const float*)d_in[11];
    const float* We2 = (const float*)d_in[12]; const float* be2 = (const float*)d_in[13];
    const float* W21 = (const float*)d_in[14]; const float* b21 = (const float*)d_in[15];
    const float* W22 = (const float*)d_in[16]; const float* b22 = (const float*)d_in[17];
    const float* g2  = (const float*)d_in[18]; const float* bt2 = (const float*)d_in[19];
    const float* We3 = (const float*)d_in[20]; const float* be3 = (const float*)d_in[21];
    const float* W31 = (const float*)d_in[22]; const float* b31 = (const float*)d_in[23];
    const float* W32 = (const float*)d_in[24]; const float* b32 = (const float*)d_in[25];
    const float* g3  = (const float*)d_in[26]; const float* bt3 = (const float*)d_in[27];
    const float* Wf1 = (const float*)d_in[28]; const float* bf1 = (const float*)d_in[29];
    const float* Wf2 = (const float*)d_in[30]; const float* bf2 = (const float*)d_in[31];

    const int N = in_sizes[0] / 7;
    const int E = in_sizes[1] / 3;
    const int G = out_size;
    const int* src = eidx;
    const int* dst = eidx + E;

    float* ws = (float*)d_ws;
    float* buf_h   = ws;                          // N*128
    float* buf_agg = buf_h + (size_t)N * HID;     // N*128
    float* buf_t   = buf_agg + (size_t)N * HID;   // N*128
    float* bnsums  = buf_t + (size_t)N * HID;     // 256
    float* bnab    = bnsums + 256;                // 256
    float* pools   = bnab + 256;                  // G*128
    float* cntp    = pools + (size_t)G * HID;     // G
    float4* epack  = (float4*)(cntp + G);         // E float4 (16B-aligned: offset is even)
    unsigned short* h16 = (unsigned short*)(epack + E);  // N*128 bf16
    int*   icnt    = (int*)(h16 + (size_t)N * HID); // N
    int*   ioffs   = icnt + N;                    // N+1
    int*   icur    = ioffs + N + 1;               // N
    int*   ipart   = icur + N;                    // 256
    int*   iexcl   = ipart + 256;                 // N

    const long long NH = (long long)N * HID;
    const int blk = 256;
    const unsigned grid_nh2  = (unsigned)((NH / 2 + blk - 1) / blk);
    const unsigned grid_nh   = (unsigned)((NH + blk - 1) / blk);
    const unsigned grid_gemm = (unsigned)(((long long)N * 32 + blk - 1) / blk);
    const unsigned grid_tile = (unsigned)((N + 63) / 64);
    const unsigned grid_bn   = (unsigned)((N + 511) / 512);
    const unsigned grid_E    = (unsigned)((E + blk - 1) / blk);
    const unsigned nb_scan   = (unsigned)((N + 255) / 256);
    const unsigned grid_gather = (unsigned)((N + 3) / 4);
    const unsigned grid_gat7 = (unsigned)(((long long)N * 8 + blk - 1) / blk);

    // ---------- build CSR with packed edges ----------
    hipMemsetAsync(icnt, 0, (size_t)N * sizeof(int), stream);
    hist_kernel<<<grid_E, blk, 0, stream>>>(dst, icnt, E);
    scan_block<<<nb_scan, 256, 0, stream>>>(icnt, iexcl, ipart, N);
    scan_partials<<<1, 256, 0, stream>>>(ipart, nb_scan, ioffs, N, E);
    scan_add<<<nb_scan, 256, 0, stream>>>(iexcl, ipart, ioffs, icur, N);
    fill_kernel<<<grid_E, blk, 0, stream>>>(dst, src, ea, icur, epack, E);

    // ---------- layer 1 ----------
    gather_d7<<<grid_gat7, blk, 0, stream>>>(x, epack, ioffs, We1, be1, buf_agg, N);
    mlp_gemm<7, true, true><<<grid_gemm, blk, 0, stream>>>(x, buf_agg, W11, b11, buf_t, N);
    gemm128_tiled<false, false><<<grid_tile, 256, 0, stream>>>(buf_t, nullptr, W12, b12, buf_agg, N);
    hipMemsetAsync(bnsums, 0, 256 * sizeof(float), stream);
    bn_stats<<<grid_bn, blk, 0, stream>>>(buf_agg, bnsums, N);
    bn_finalize<<<1, 128, 0, stream>>>(bnsums, g1, bt1, bnab, N);
    bn_apply_relu<true><<<grid_nh2, blk, 0, stream>>>(buf_agg, bnab, buf_h, h16, NH);

    // ---------- layer 2 ----------
    gather_d128<<<grid_gather, 256, 0, stream>>>(h16, epack, ioffs, We2, be2, buf_agg, N);
    gemm128_tiled<true, true><<<grid_tile, 256, 0, stream>>>(buf_h, buf_agg, W21, b21, buf_t, N);
    gemm128_tiled<false, false><<<grid_tile, 256, 0, stream>>>(buf_t, nullptr, W22, b22, buf_agg, N);
    hipMemsetAsync(bnsums, 0, 256 * sizeof(float), stream);
    bn_stats<<<grid_bn, blk, 0, stream>>>(buf_agg, bnsums, N);
    bn_finalize<<<1, 128, 0, stream>>>(bnsums, g2, bt2, bnab, N);
    bn_apply_relu<true><<<grid_nh2, blk, 0, stream>>>(buf_agg, bnab, buf_h, h16, NH);

    // ---------- layer 3 ----------
    gather_d128<<<grid_gather, 256, 0, stream>>>(h16, epack, ioffs, We3, be3, buf_agg, N);
    gemm128_tiled<true, true><<<grid_tile, 256, 0, stream>>>(buf_h, buf_agg, W31, b31, buf_t, N);
    gemm128_tiled<false, false><<<grid_tile, 256, 0, stream>>>(buf_t, nullptr, W32, b32, buf_agg, N);
    hipMemsetAsync(bnsums, 0, 256 * sizeof(float), stream);
    bn_stats<<<grid_bn, blk, 0, stream>>>(buf_agg, bnsums, N);
    bn_finalize<<<1, 128, 0, stream>>>(bnsums, g3, bt3, bnab, N);
    bn_apply_relu<false><<<grid_nh2, blk, 0, stream>>>(buf_agg, bnab, buf_h, nullptr, NH);

    // ---------- pool + head ----------
    hipMemsetAsync(pools, 0, ((size_t)G * HID + G) * sizeof(float), stream);
    pool_scatter<<<grid_nh, blk, 0, stream>>>(buf_h, batch, pools, cntp, N);
    head_kernel<<<G, 64, 0, stream>>>(pools, cntp, Wf1, bf1, Wf2, bf2, (float*)d_out, G);
}

// Round 6
// 683.301 us; speedup vs baseline: 2.9884x; 1.3370x over previous
//
#include <hip/hip_runtime.h>

#define HID 128

struct F4 { float v[4]; };

__device__ inline unsigned short f2bf(float f) {
    unsigned u = __float_as_uint(f);
    unsigned r = (u + 0x7fff + ((u >> 16) & 1)) >> 16;
    return (unsigned short)r;
}
__device__ inline float bf2f(unsigned short b) {
    return __uint_as_float(((unsigned)b) << 16);
}

// ================= CSR build =================
__global__ void hist_kernel(const int* __restrict__ dst, int* __restrict__ cnt, int E)
{
    int e = blockIdx.x * blockDim.x + threadIdx.x;
    if (e < E) atomicAdd(&cnt[dst[e]], 1);
}

__global__ void scan_block(const int* __restrict__ cnt, int* __restrict__ excl,
                           int* __restrict__ partials, int Nn)
{
    __shared__ int ls[256];
    int i = blockIdx.x * 256 + threadIdx.x;
    int v = (i < Nn) ? cnt[i] : 0;
    ls[threadIdx.x] = v;
    __syncthreads();
    for (int off = 1; off < 256; off <<= 1) {
        int t = (threadIdx.x >= off) ? ls[threadIdx.x - off] : 0;
        __syncthreads();
        ls[threadIdx.x] += t;
        __syncthreads();
    }
    if (i < Nn) excl[i] = ls[threadIdx.x] - v;
    if (threadIdx.x == 255) partials[blockIdx.x] = ls[255];
}

__global__ void scan_partials(int* __restrict__ partials, int nb, int* __restrict__ offsets,
                              int Nn, int E)
{
    __shared__ int ls[256];
    int t = threadIdx.x;
    int v = (t < nb) ? partials[t] : 0;
    ls[t] = v;
    __syncthreads();
    for (int off = 1; off < 256; off <<= 1) {
        int x = (t >= off) ? ls[t - off] : 0;
        __syncthreads();
        ls[t] += x;
        __syncthreads();
    }
    if (t < nb) partials[t] = ls[t] - v;
    if (t == 0) offsets[Nn] = E;
}

__global__ void scan_add(const int* __restrict__ excl, const int* __restrict__ partials,
                         int* __restrict__ offsets, int* __restrict__ cursor, int Nn)
{
    int i = blockIdx.x * 256 + threadIdx.x;
    if (i < Nn) {
        int o = excl[i] + partials[blockIdx.x];
        offsets[i] = o;
        cursor[i] = o;
    }
}

__global__ void fill_kernel(const int* __restrict__ dst, const int* __restrict__ src,
                            const float* __restrict__ ea, int* __restrict__ cursor,
                            float4* __restrict__ epack, int E)
{
    int e = blockIdx.x * blockDim.x + threadIdx.x;
    if (e < E) {
        int pos = atomicAdd(&cursor[dst[e]], 1);
        float4 p;
        p.x = __int_as_float(src[e]);
        p.y = ea[e * 3];
        p.z = ea[e * 3 + 1];
        p.w = ea[e * 3 + 2];
        epack[pos] = p;
    }
}

// ================= layer 1: CSR gather (dim 7) =================
__global__ void gather_d7(const float* __restrict__ x, const float4* __restrict__ epack,
                          const int* __restrict__ offsets,
                          const float* __restrict__ We, const float* __restrict__ be,
                          float* __restrict__ agg, int Nn)
{
    int tid = blockIdx.x * blockDim.x + threadIdx.x;
    int node = tid >> 3;
    int c = tid & 7;
    if (node >= Nn) return;
    float w0 = 0.f, w1 = 0.f, w2 = 0.f, b = 0.f;
    if (c < 7) { w0 = We[c]; w1 = We[7 + c]; w2 = We[14 + c]; b = be[c]; }
    int beg = offsets[node], end = offsets[node + 1];
    float acc = 0.f;
    for (int i = beg; i < end; ++i) {
        float4 ep = epack[i];
        int s = __float_as_int(ep.x);
        float v = b;
        v = fmaf(ep.y, w0, v);
        v = fmaf(ep.z, w1, v);
        v = fmaf(ep.w, w2, v);
        if (c < 7) v += x[s * 7 + c];
        acc += fmaxf(v, 0.f);
    }
    if (c < 7) agg[node * 7 + c] = acc;
}

// ================= layers 2/3: gather, 4x unrolled, writes h+agg =================
__global__ void gather_d128(const unsigned short* __restrict__ h16,
                            const float4* __restrict__ epack,
                            const int* __restrict__ offsets,
                            const float* __restrict__ We, const float* __restrict__ be,
                            const float* __restrict__ hprev,
                            float* __restrict__ agg, int Nn)
{
    int node = blockIdx.x * (blockDim.x >> 6) + (threadIdx.x >> 6);
    if (node >= Nn) return;
    int lane = threadIdx.x & 63;
    int beg = offsets[node], end = offsets[node + 1];
    const float2* W2 = (const float2*)We;
    float2 w0 = W2[lane];
    float2 w1 = W2[64 + lane];
    float2 w2 = W2[128 + lane];
    float2 bb = ((const float2*)be)[lane];
    float accx = 0.f, accy = 0.f;

    int i = beg;
    for (; i + 4 <= end; i += 4) {
        float4 e0 = epack[i], e1 = epack[i + 1], e2 = epack[i + 2], e3 = epack[i + 3];
        ushort2 p0 = ((const ushort2*)(h16 + (size_t)__float_as_int(e0.x) * HID))[lane];
        ushort2 p1 = ((const ushort2*)(h16 + (size_t)__float_as_int(e1.x) * HID))[lane];
        ushort2 p2 = ((const ushort2*)(h16 + (size_t)__float_as_int(e2.x) * HID))[lane];
        ushort2 p3 = ((const ushort2*)(h16 + (size_t)__float_as_int(e3.x) * HID))[lane];
        float vx, vy;
        vx = bb.x + bf2f(p0.x);
        vx = fmaf(e0.y, w0.x, vx); vx = fmaf(e0.z, w1.x, vx); vx = fmaf(e0.w, w2.x, vx);
        vy = bb.y + bf2f(p0.y);
        vy = fmaf(e0.y, w0.y, vy); vy = fmaf(e0.z, w1.y, vy); vy = fmaf(e0.w, w2.y, vy);
        accx += fmaxf(vx, 0.f); accy += fmaxf(vy, 0.f);
        vx = bb.x + bf2f(p1.x);
        vx = fmaf(e1.y, w0.x, vx); vx = fmaf(e1.z, w1.x, vx); vx = fmaf(e1.w, w2.x, vx);
        vy = bb.y + bf2f(p1.y);
        vy = fmaf(e1.y, w0.y, vy); vy = fmaf(e1.z, w1.y, vy); vy = fmaf(e1.w, w2.y, vy);
        accx += fmaxf(vx, 0.f); accy += fmaxf(vy, 0.f);
        vx = bb.x + bf2f(p2.x);
        vx = fmaf(e2.y, w0.x, vx); vx = fmaf(e2.z, w1.x, vx); vx = fmaf(e2.w, w2.x, vx);
        vy = bb.y + bf2f(p2.y);
        vy = fmaf(e2.y, w0.y, vy); vy = fmaf(e2.z, w1.y, vy); vy = fmaf(e2.w, w2.y, vy);
        accx += fmaxf(vx, 0.f); accy += fmaxf(vy, 0.f);
        vx = bb.x + bf2f(p3.x);
        vx = fmaf(e3.y, w0.x, vx); vx = fmaf(e3.z, w1.x, vx); vx = fmaf(e3.w, w2.x, vx);
        vy = bb.y + bf2f(p3.y);
        vy = fmaf(e3.y, w0.y, vy); vy = fmaf(e3.z, w1.y, vy); vy = fmaf(e3.w, w2.y, vy);
        accx += fmaxf(vx, 0.f); accy += fmaxf(vy, 0.f);
    }
    for (; i < end; ++i) {
        float4 ep = epack[i];
        ushort2 hp = ((const ushort2*)(h16 + (size_t)__float_as_int(ep.x) * HID))[lane];
        float vx = bb.x + bf2f(hp.x);
        vx = fmaf(ep.y, w0.x, vx); vx = fmaf(ep.z, w1.x, vx); vx = fmaf(ep.w, w2.x, vx);
        float vy = bb.y + bf2f(hp.y);
        vy = fmaf(ep.y, w0.y, vy); vy = fmaf(ep.z, w1.y, vy); vy = fmaf(ep.w, w2.y, vy);
        accx += fmaxf(vx, 0.f);
        accy += fmaxf(vy, 0.f);
    }
    // add node's own h row (GINE: h + agg), coalesced
    float2 hv = ((const float2*)(hprev + (size_t)node * HID))[lane];
    float2 outv = {accx + hv.x, accy + hv.y};
    ((float2*)(agg + (size_t)node * HID))[lane] = outv;
}

// ================= tiled fp32 GEMM, optional fused BN-stats =================
template <bool HASADD, bool RELU, bool STATS>
__global__ __launch_bounds__(256) void gemm128_tiled(const float* __restrict__ A,
                                                     const float* __restrict__ A2,
                                                     const float* __restrict__ W,
                                                     const float* __restrict__ bias,
                                                     float* __restrict__ C,
                                                     float* __restrict__ bnsums, int N)
{
    __shared__ float As[64 * 128];
    __shared__ float sls[128], slq[128];
    int t = threadIdx.x;
    int nb = blockIdx.x * 64;
    {
        const float4* A4 = (const float4*)(A + (size_t)nb * HID);
        const float4* B4 = (const float4*)(HASADD ? (A2 + (size_t)nb * HID) : nullptr);
        int limit4 = 32 * (N - nb < 64 ? (N - nb) : 64);
#pragma unroll
        for (int i = 0; i < 8; ++i) {
            int idx = t + i * 256;
            float4 v = {0.f, 0.f, 0.f, 0.f};
            if (idx < limit4) {
                v = A4[idx];
                if (HASADD) {
                    float4 u = B4[idx];
                    v.x += u.x; v.y += u.y; v.z += u.z; v.w += u.w;
                }
            }
            ((float4*)As)[idx] = v;
        }
        if (STATS && t < 128) { sls[t] = 0.f; slq[t] = 0.f; }
    }
    __syncthreads();

    int c8 = t & 15;
    int ng = t >> 4;
    const float4* W4 = (const float4*)W;
    float4 acc[4][2];
    {
        const float4* Bb = (const float4*)bias;
        float4 b0 = Bb[c8 * 2], b1 = Bb[c8 * 2 + 1];
#pragma unroll
        for (int j = 0; j < 4; ++j) { acc[j][0] = b0; acc[j][1] = b1; }
    }
    const float* As0 = As + ng * 4 * HID;
#pragma unroll 4
    for (int k = 0; k < HID; k += 4) {
        F4 a[4];
#pragma unroll
        for (int j = 0; j < 4; ++j) a[j] = *(const F4*)(As0 + j * HID + k);
#pragma unroll
        for (int kk = 0; kk < 4; ++kk) {
            float4 w0 = W4[(k + kk) * 32 + c8 * 2];
            float4 w1 = W4[(k + kk) * 32 + c8 * 2 + 1];
#pragma unroll
            for (int j = 0; j < 4; ++j) {
                float av = a[j].v[kk];
                acc[j][0].x = fmaf(av, w0.x, acc[j][0].x);
                acc[j][0].y = fmaf(av, w0.y, acc[j][0].y);
                acc[j][0].z = fmaf(av, w0.z, acc[j][0].z);
                acc[j][0].w = fmaf(av, w0.w, acc[j][0].w);
                acc[j][1].x = fmaf(av, w1.x, acc[j][1].x);
                acc[j][1].y = fmaf(av, w1.y, acc[j][1].y);
                acc[j][1].z = fmaf(av, w1.z, acc[j][1].z);
                acc[j][1].w = fmaf(av, w1.w, acc[j][1].w);
            }
        }
    }
    float s8[8], q8[8];
    if (STATS) {
#pragma unroll
        for (int u = 0; u < 8; ++u) { s8[u] = 0.f; q8[u] = 0.f; }
    }
#pragma unroll
    for (int j = 0; j < 4; ++j) {
        int n = nb + ng * 4 + j;
        if (n >= N) break;
        float4 o0 = acc[j][0], o1 = acc[j][1];
        if (RELU) {
            o0.x = fmaxf(o0.x, 0.f); o0.y = fmaxf(o0.y, 0.f);
            o0.z = fmaxf(o0.z, 0.f); o0.w = fmaxf(o0.w, 0.f);
            o1.x = fmaxf(o1.x, 0.f); o1.y = fmaxf(o1.y, 0.f);
            o1.z = fmaxf(o1.z, 0.f); o1.w = fmaxf(o1.w, 0.f);
        }
        if (STATS) {
            const float* ov = (const float*)&o0;
#pragma unroll
            for (int u = 0; u < 4; ++u) { s8[u] += ov[u]; q8[u] = fmaf(ov[u], ov[u], q8[u]); }
            const float* ov1 = (const float*)&o1;
#pragma unroll
            for (int u = 0; u < 4; ++u) { s8[4 + u] += ov1[u]; q8[4 + u] = fmaf(ov1[u], ov1[u], q8[4 + u]); }
        }
        float4* Cp = (float4*)(C + (size_t)n * HID) + c8 * 2;
        Cp[0] = o0;
        Cp[1] = o1;
    }
    if (STATS) {
#pragma unroll
        for (int u = 0; u < 8; ++u) {
            atomicAdd(&sls[c8 * 8 + u], s8[u]);
            atomicAdd(&slq[c8 * 8 + u], q8[u]);
        }
        __syncthreads();
        if (t < 128) {
            atomicAdd(&bnsums[t], sls[t]);
            atomicAdd(&bnsums[128 + t], slq[t]);
        }
    }
}

// ================= small GEMM for layer-1 (K=7) =================
template <int K, bool HASADD, bool RELU>
__global__ void mlp_gemm(const float* __restrict__ A, const float* __restrict__ A2,
                         const float* __restrict__ W, const float* __restrict__ bias,
                         float* __restrict__ C, int N)
{
    long long gid = (long long)blockIdx.x * blockDim.x + threadIdx.x;
    long long total = (long long)N * 32;
    if (gid >= total) return;
    int n = (int)(gid >> 5);
    int c4 = (int)(gid & 31);
    const float4* W4 = (const float4*)W;
    const float4* B4 = (const float4*)bias;
    float4 acc = B4[c4];
    const float* arow = A + (long long)n * K;
    const float* arow2 = A2 ? (A2 + (long long)n * K) : nullptr;
#pragma unroll 4
    for (int k = 0; k < K; ++k) {
        float a = arow[k];
        if (HASADD) a += arow2[k];
        float4 w = W4[k * 32 + c4];
        acc.x = fmaf(a, w.x, acc.x);
        acc.y = fmaf(a, w.y, acc.y);
        acc.z = fmaf(a, w.z, acc.z);
        acc.w = fmaf(a, w.w, acc.w);
    }
    if (RELU) {
        acc.x = fmaxf(acc.x, 0.f); acc.y = fmaxf(acc.y, 0.f);
        acc.z = fmaxf(acc.z, 0.f); acc.w = fmaxf(acc.w, 0.f);
    }
    ((float4*)C)[gid] = acc;
}

// ================= BN =================
__global__ void bn_finalize(const float* __restrict__ sums, const float* __restrict__ g,
                            const float* __restrict__ bt, float* __restrict__ ab, int N)
{
    int c = threadIdx.x;
    if (c < 128) {
        float inv = 1.f / (float)N;
        float mu = sums[c] * inv;
        float var = sums[128 + c] * inv - mu * mu;
        float rs = rsqrtf(fmaxf(var, 0.f) + 1e-5f);
        float a = g[c] * rs;
        ab[c] = a;
        ab[128 + c] = bt[c] - a * mu;
    }
}

template <bool W16>
__global__ void bn_apply_relu(const float* __restrict__ h, const float* __restrict__ ab,
                              float* __restrict__ out, unsigned short* __restrict__ h16,
                              long long total)
{
    long long i = ((long long)blockIdx.x * blockDim.x + threadIdx.x) * 2;
    if (i >= total) return;
    int c = (int)(i & 127);
    float2 hv = *(const float2*)(h + i);
    float v0 = fmaxf(fmaf(hv.x, ab[c], ab[128 + c]), 0.f);
    float v1 = fmaxf(fmaf(hv.y, ab[c + 1], ab[129 + c]), 0.f);
    float2 ov = {v0, v1};
    *(float2*)(out + i) = ov;
    if (W16) {
        unsigned pair = (unsigned)f2bf(v0) | ((unsigned)f2bf(v1) << 16);
        *(unsigned*)(h16 + i) = pair;
    }
}

// ================= fused layer-3 BN-apply + mean-pool scatter =================
__global__ void bn_pool(const float* __restrict__ agg, const float* __restrict__ ab,
                        const int* __restrict__ batch,
                        float* __restrict__ pools, float* __restrict__ cnt, int N)
{
    long long i = (long long)blockIdx.x * blockDim.x + threadIdx.x;
    long long total = (long long)N * HID;
    if (i >= total) return;
    int n = (int)(i >> 7);
    int c = (int)(i & 127);
    int g = batch[n];
    float v = fmaxf(fmaf(agg[i], ab[c], ab[128 + c]), 0.f);
    atomicAdd(&pools[(long long)g * HID + c], v);
    if (c == 0) atomicAdd(&cnt[g], 1.f);
}

__global__ void head_kernel(const float* __restrict__ pools, const float* __restrict__ cnt,
                            const float* __restrict__ Wf1, const float* __restrict__ bf1,
                            const float* __restrict__ Wf2, const float* __restrict__ bf2,
                            float* __restrict__ out, int G)
{
    int g = blockIdx.x;
    int t = threadIdx.x;
    __shared__ float p[128];
    float inv = 1.f / fmaxf(cnt[g], 1.f);
    p[t] = pools[g * 128 + t] * inv;
    p[t + 64] = pools[g * 128 + t + 64] * inv;
    __syncthreads();
    float o = bf1[t];
#pragma unroll 8
    for (int k = 0; k < 128; ++k) o = fmaf(p[k], Wf1[k * 64 + t], o);
    o = fmaxf(o, 0.f);
    float prod = o * Wf2[t];
#pragma unroll
    for (int off = 32; off > 0; off >>= 1) prod += __shfl_down(prod, off);
    if (t == 0) out[g] = prod + bf2[0];
}

extern "C" void kernel_launch(void* const* d_in, const int* in_sizes, int n_in,
                              void* d_out, int out_size, void* d_ws, size_t ws_size,
                              hipStream_t stream)
{
    const float* x     = (const float*)d_in[0];
    const float* ea    = (const float*)d_in[1];
    const int*   eidx  = (const int*)d_in[2];
    const int*   batch = (const int*)d_in[3];
    const float* We1 = (const float*)d_in[4];  const float* be1 = (const float*)d_in[5];
    const float* W11 = (const float*)d_in[6];  const float* b11 = (const float*)d_in[7];
    const float* W12 = (const float*)d_in[8];  const float* b12 = (const float*)d_in[9];
    const float* g1  = (const float*)d_in[10]; const float* bt1 = (const float*)d_in[11];
    const float* We2 = (const float*)d_in[12]; const float* be2 = (const float*)d_in[13];
    const float* W21 = (const float*)d_in[14]; const float* b21 = (const float*)d_in[15];
    const float* W22 = (const float*)d_in[16]; const float* b22 = (const float*)d_in[17];
    const float* g2  = (const float*)d_in[18]; const float* bt2 = (const float*)d_in[19];
    const float* We3 = (const float*)d_in[20]; const float* be3 = (const float*)d_in[21];
    const float* W31 = (const float*)d_in[22]; const float* b31 = (const float*)d_in[23];
    const float* W32 = (const float*)d_in[24]; const float* b32 = (const float*)d_in[25];
    const float* g3  = (const float*)d_in[26]; const float* bt3 = (const float*)d_in[27];
    const float* Wf1 = (const float*)d_in[28]; const float* bf1 = (const float*)d_in[29];
    const float* Wf2 = (const float*)d_in[30]; const float* bf2 = (const float*)d_in[31];

    const int N = in_sizes[0] / 7;
    const int E = in_sizes[1] / 3;
    const int G = out_size;
    const int* src = eidx;
    const int* dst = eidx + E;

    float* ws = (float*)d_ws;
    float* buf_h   = ws;                          // N*128
    float* buf_agg = buf_h + (size_t)N * HID;     // N*128
    float* buf_t   = buf_agg + (size_t)N * HID;   // N*128
    float* bnsums  = buf_t + (size_t)N * HID;     // 256
    float* bnab    = bnsums + 256;                // 256
    float* pools   = bnab + 256;                  // G*128
    float* cntp    = pools + (size_t)G * HID;     // G
    float4* epack  = (float4*)(cntp + G);         // E float4
    unsigned short* h16 = (unsigned short*)(epack + E);  // N*128 bf16
    int*   icnt    = (int*)(h16 + (size_t)N * HID); // N
    int*   ioffs   = icnt + N;                    // N+1
    int*   icur    = ioffs + N + 1;               // N
    int*   ipart   = icur + N;                    // 256
    int*   iexcl   = ipart + 256;                 // N

    const long long NH = (long long)N * HID;
    const int blk = 256;
    const unsigned grid_nh2  = (unsigned)((NH / 2 + blk - 1) / blk);
    const unsigned grid_nh   = (unsigned)((NH + blk - 1) / blk);
    const unsigned grid_gemm = (unsigned)(((long long)N * 32 + blk - 1) / blk);
    const unsigned grid_tile = (unsigned)((N + 63) / 64);
    const unsigned grid_E    = (unsigned)((E + blk - 1) / blk);
    const unsigned nb_scan   = (unsigned)((N + 255) / 256);
    const unsigned grid_gather = (unsigned)((N + 3) / 4);
    const unsigned grid_gat7 = (unsigned)(((long long)N * 8 + blk - 1) / blk);

    // ---------- build CSR with packed edges ----------
    hipMemsetAsync(icnt, 0, (size_t)N * sizeof(int), stream);
    hist_kernel<<<grid_E, blk, 0, stream>>>(dst, icnt, E);
    scan_block<<<nb_scan, 256, 0, stream>>>(icnt, iexcl, ipart, N);
    scan_partials<<<1, 256, 0, stream>>>(ipart, nb_scan, ioffs, N, E);
    scan_add<<<nb_scan, 256, 0, stream>>>(iexcl, ipart, ioffs, icur, N);
    fill_kernel<<<grid_E, blk, 0, stream>>>(dst, src, ea, icur, epack, E);

    // ---------- layer 1 ----------
    hipMemsetAsync(bnsums, 0, 256 * sizeof(float), stream);
    gather_d7<<<grid_gat7, blk, 0, stream>>>(x, epack, ioffs, We1, be1, buf_agg, N);
    mlp_gemm<7, true, true><<<grid_gemm, blk, 0, stream>>>(x, buf_agg, W11, b11, buf_t, N);
    gemm128_tiled<false, false, true><<<grid_tile, 256, 0, stream>>>(buf_t, nullptr, W12, b12, buf_agg, bnsums, N);
    bn_finalize<<<1, 128, 0, stream>>>(bnsums, g1, bt1, bnab, N);
    bn_apply_relu<true><<<grid_nh2, blk, 0, stream>>>(buf_agg, bnab, buf_h, h16, NH);

    // ---------- layer 2 ----------
    hipMemsetAsync(bnsums, 0, 256 * sizeof(float), stream);
    gather_d128<<<grid_gather, 256, 0, stream>>>(h16, epack, ioffs, We2, be2, buf_h, buf_agg, N);
    gemm128_tiled<false, true, false><<<grid_tile, 256, 0, stream>>>(buf_agg, nullptr, W21, b21, buf_t, nullptr, N);
    gemm128_tiled<false, false, true><<<grid_tile, 256, 0, stream>>>(buf_t, nullptr, W22, b22, buf_agg, bnsums, N);
    bn_finalize<<<1, 128, 0, stream>>>(bnsums, g2, bt2, bnab, N);
    bn_apply_relu<true><<<grid_nh2, blk, 0, stream>>>(buf_agg, bnab, buf_h, h16, NH);

    // ---------- layer 3 ----------
    hipMemsetAsync(bnsums, 0, 256 * sizeof(float), stream);
    gather_d128<<<grid_gather, 256, 0, stream>>>(h16, epack, ioffs, We3, be3, buf_h, buf_agg, N);
    gemm128_tiled<false, true, false><<<grid_tile, 256, 0, stream>>>(buf_agg, nullptr, W31, b31, buf_t, nullptr, N);
    gemm128_tiled<false, false, true><<<grid_tile, 256, 0, stream>>>(buf_t, nullptr, W32, b32, buf_agg, bnsums, N);
    bn_finalize<<<1, 128, 0, stream>>>(bnsums, g3, bt3, bnab, N);

    // ---------- fused BN-apply + pool, then head ----------
    hipMemsetAsync(pools, 0, ((size_t)G * HID + G) * sizeof(float), stream);
    bn_pool<<<grid_nh, blk, 0, stream>>>(buf_agg, bnab, batch, pools, cntp, N);
    head_kernel<<<G, 64, 0, stream>>>(pools, cntp, Wf1, bf1, Wf2, bf2, (float*)d_out, G);
}